// Round 8
// baseline (581.963 us; speedup 1.0000x reference)
//
#include <hip/hip_runtime.h>
#include <hip/hip_bf16.h>
#include <math.h>

// Problem constants
constexpr int kD   = 256;   // model dim
constexpr int kH   = 4;     // heads
constexpr int kHD  = 64;    // head dim
constexpr int kB   = 2;
constexpr int kN   = 6;     // views
constexpr int kM   = 512;   // keypoints (M == NS)
constexpr int kRowsH = kB*kN*kM;          // 6144 rows per half (t or s)
constexpr int kRows  = 2*kRowsH;          // 12288 merged rows
constexpr int kGrpH  = kB*kN*kH;          // 48 attention groups per half
constexpr int kGrp   = 2*kGrpH;           // 96 merged groups
constexpr size_t kTOK = (size_t)kRowsH*kD;        // 1,572,864
constexpr size_t kEncSlab = (size_t)kN*kM*kHD;    // 196608
constexpr size_t kQEncSlab = (size_t)kN*kN*kHD;   // 2304
constexpr float kL2E = 1.4426950408889634f;

typedef unsigned short u16;
typedef __attribute__((ext_vector_type(8))) short s16x8;
typedef __attribute__((ext_vector_type(4))) float f32x4;

__device__ __forceinline__ float wred_sum(float v){
  #pragma unroll
  for (int m=32;m>0;m>>=1) v += __shfl_xor(v, m, 64);
  return v;
}
__device__ __forceinline__ u16 f2b(float x){
  union { float f; unsigned u; } a; a.f = x;
  unsigned r = a.u + 0x7fffu + ((a.u >> 16) & 1u);
  return (u16)(r >> 16);
}
__device__ __forceinline__ float b2f(u16 x){
  union { unsigned u; float f; } a; a.u = ((unsigned)x) << 16;
  return a.f;
}
// pack two f32 -> u32 of {lo16=bf16(lo), hi16=bf16(hi)}
__device__ __forceinline__ unsigned pk2(float lo, float hi){
  union { __hip_bfloat162 h2; unsigned u; } c;
  c.h2 = __float22bfloat162_rn(make_float2(lo, hi));
  return c.u;
}
__device__ __forceinline__ f32x4 vmax4(f32x4 a, f32x4 b){
  f32x4 r;
  r[0]=fmaxf(a[0],b[0]); r[1]=fmaxf(a[1],b[1]);
  r[2]=fmaxf(a[2],b[2]); r[3]=fmaxf(a[3],b[3]);
  return r;
}

// ---------------------------------------------------------------------------
// Weight transpose+cast: W[K][N] f32 -> Wt[N][K] bf16. Batched over matrices.
// ---------------------------------------------------------------------------
struct WtDesc { const float* W; u16* Wt; int K; int N; int ntiles; };
struct WtTable { WtDesc d[18]; };

__global__ __launch_bounds__(256) void wtcast_k(WtTable tab)
{
  int t = blockIdx.x, mi = 0;
  while (t >= tab.d[mi].ntiles) { t -= tab.d[mi].ntiles; ++mi; }
  const float* W = tab.d[mi].W;
  u16* Wt = tab.d[mi].Wt;
  const int K = tab.d[mi].K, N = tab.d[mi].N;
  const int ntn = N >> 5;
  const int n0 = (t % ntn) * 32, k0 = (t / ntn) * 32;
  __shared__ float tile[32][33];
  const int tx = threadIdx.x & 31, ty = threadIdx.x >> 5;
  #pragma unroll
  for (int i = 0; i < 32; i += 8)
    tile[ty+i][tx] = W[(size_t)(k0+ty+i)*N + n0+tx];
  __syncthreads();
  #pragma unroll
  for (int i = 0; i < 32; i += 8)
    Wt[(size_t)(n0+ty+i)*K + k0+tx] = f2b(tile[tx][ty+i]);
}

// ---------------------------------------------------------------------------
// bf16 MFMA GEMM, dual row-segment (rows<Mh: seg a, else seg b) and dual
// col-segment bias (cols<Ns: bias, else bias2).
// ---------------------------------------------------------------------------
template<bool A1B, bool A2B, bool CB>
__global__ __launch_bounds__(256) void mmad_k(
    const void* __restrict__ A1a, const void* __restrict__ A1b,
    const void* __restrict__ A2a, const void* __restrict__ A2b, int K1,
    const u16* __restrict__ Wa, const u16* __restrict__ Wb,
    const float* __restrict__ bia, const float* __restrict__ bib,
    const float* __restrict__ bi2a, const float* __restrict__ bi2b, int Ns,
    const float* __restrict__ Ra, const float* __restrict__ Rb,
    void* __restrict__ Cp, int N, int K, int Mh, int doRelu)
{
  __shared__ u16 As[128*32];
  __shared__ u16 Bs[128*32];
  const int tid = threadIdx.x;
  const int lane = tid & 63, w = tid >> 6;
  const int row0 = blockIdx.y*128, col0 = blockIdx.x*128;
  const bool sec = (row0 >= Mh);
  const int lr0 = sec ? row0 - Mh : row0;
  const void* A1 = sec ? A1b : A1a;
  const void* A2 = sec ? A2b : A2a;
  const u16* Wt  = sec ? Wb : Wa;
  const float* bias  = sec ? bib : bia;
  const float* bias2 = sec ? bi2b : bi2a;
  const float* R = sec ? Rb : Ra;
  const int wr = (w >> 1)*64, wc = (w & 1)*64;
  const int ar = tid >> 1, ah = tid & 1;
  const int K2 = K - K1;
  f32x4 acc[4][4] = {};

  for (int kt = 0; kt < K; kt += 32) {
    const int kk = kt + ah*16;
    union { u16 u[16]; s16x8 v[2]; } tmp;
    if (kk < K1) {
      if constexpr (A1B) {
        const u16* ap = (const u16*)A1 + (size_t)(lr0+ar)*K1 + kk;
        tmp.v[0] = *(const s16x8*)ap; tmp.v[1] = *(const s16x8*)(ap+8);
      } else {
        const float* ap = (const float*)A1 + (size_t)(lr0+ar)*K1 + kk;
        #pragma unroll
        for (int i = 0; i < 16; i += 4) {
          f32x4 v4 = *(const f32x4*)(ap + i);
          tmp.u[i+0]=f2b(v4.x); tmp.u[i+1]=f2b(v4.y); tmp.u[i+2]=f2b(v4.z); tmp.u[i+3]=f2b(v4.w);
        }
      }
    } else {
      if constexpr (A2B) {
        const u16* ap = (const u16*)A2 + (size_t)(lr0+ar)*K2 + (kk - K1);
        tmp.v[0] = *(const s16x8*)ap; tmp.v[1] = *(const s16x8*)(ap+8);
      } else {
        const float* ap = (const float*)A2 + (size_t)(lr0+ar)*K2 + (kk - K1);
        #pragma unroll
        for (int i = 0; i < 16; i += 4) {
          f32x4 v4 = *(const f32x4*)(ap + i);
          tmp.u[i+0]=f2b(v4.x); tmp.u[i+1]=f2b(v4.y); tmp.u[i+2]=f2b(v4.z); tmp.u[i+3]=f2b(v4.w);
        }
      }
    }
    const int sw = (ar >> 1) & 3;
    *(s16x8*)(&As[ar*32 + ((ah*2+0)^sw)*8]) = tmp.v[0];
    *(s16x8*)(&As[ar*32 + ((ah*2+1)^sw)*8]) = tmp.v[1];
    {
      const u16* bp = Wt + (size_t)(col0+ar)*K + kt + ah*16;
      s16x8 b0 = *(const s16x8*)(bp);
      s16x8 b1 = *(const s16x8*)(bp + 8);
      *(s16x8*)(&Bs[ar*32 + ((ah*2+0)^sw)*8]) = b0;
      *(s16x8*)(&Bs[ar*32 + ((ah*2+1)^sw)*8]) = b1;
    }
    __syncthreads();
    s16x8 af[4], bfv[4];
    #pragma unroll
    for (int fm = 0; fm < 4; ++fm) {
      const int r = wr + fm*16 + (lane & 15);
      const int g = (lane >> 4) ^ ((r >> 1) & 3);
      af[fm] = *(const s16x8*)(&As[r*32 + g*8]);
    }
    #pragma unroll
    for (int fn = 0; fn < 4; ++fn) {
      const int c = wc + fn*16 + (lane & 15);
      const int g = (lane >> 4) ^ ((c >> 1) & 3);
      bfv[fn] = *(const s16x8*)(&Bs[c*32 + g*8]);
    }
    #pragma unroll
    for (int fm = 0; fm < 4; ++fm)
      #pragma unroll
      for (int fn = 0; fn < 4; ++fn)
        acc[fm][fn] = __builtin_amdgcn_mfma_f32_16x16x32_bf16(af[fm], bfv[fn], acc[fm][fn], 0, 0, 0);
    __syncthreads();
  }

  #pragma unroll
  for (int fm = 0; fm < 4; ++fm) {
    const int ro = wr + fm*16 + (lane >> 4)*4;
    #pragma unroll
    for (int fn = 0; fn < 4; ++fn) {
      const int cc = col0 + wc + fn*16 + (lane & 15);
      const float bv = (cc < Ns) ? bias[cc] : bias2[cc - Ns];
      #pragma unroll
      for (int j = 0; j < 4; ++j) {
        float v = acc[fm][fn][j] + bv;
        if (R) v += R[(size_t)(lr0 + ro + j)*N + cc];
        if (doRelu) v = fmaxf(v, 0.f);
        const size_t idx = (size_t)(row0 + ro + j)*N + cc;
        if constexpr (CB) ((u16*)Cp)[idx] = f2b(v);
        else              ((float*)Cp)[idx] = v;
      }
    }
  }
}

// ---------------------------------------------------------------------------
// Preps (read bf16 qkv/kv): emit bf16 K [g][key][64], bf16 Vt [g][64][key],
// and Q (self: roped+0.125-prescaled bf16; s2s: raw f32; cross: K prescaled).
// ---------------------------------------------------------------------------
__global__ __launch_bounds__(256) void prep_self_k(
    const u16* __restrict__ qkvU, const float* __restrict__ t_enc,
    const float* __restrict__ s_enc,
    u16* __restrict__ Qb, u16* __restrict__ Kb, u16* __restrict__ Vt)
{
  __shared__ u16 vs[64][66];
  const int g = blockIdx.x >> 3, i0 = (blockIdx.x & 7)*64;
  const int h = g & 3, bn = g >> 2;                 // bn 0..23 (t:0-11, s:12-23)
  const float* enc = (bn < 12) ? t_enc : s_enc;
  const int n = (bn < 12 ? bn : bn - 12) % kN;
  const int c = threadIdx.x & 63, t4 = threadIdx.x >> 6;
  const float sgn = (c & 1) ? 1.f : -1.f;
  #pragma unroll 4
  for (int rr = 0; rr < 16; ++rr) {
    const int il = rr*4 + t4, i = i0 + il;
    const u16* base = qkvU + ((size_t)bn*kM + i)*768 + h*192;
    const float q = b2f(base[c*3]), k = b2f(base[c*3+1]);
    const float qp = b2f(base[(c^1)*3]), kp = b2f(base[(c^1)*3+1]);
    const size_t eo = ((size_t)(n*kM + i))*kHD + c;
    const float e0 = enc[eo], e1 = enc[kEncSlab + eo];
    Qb[((size_t)g*kM + i)*kHD + c] = f2b((q*e0 + sgn*qp*e1)*0.125f);
    Kb[((size_t)g*kM + i)*kHD + c] = f2b(k*e0 + sgn*kp*e1);
    vs[il][c] = base[c*3+2];
  }
  __syncthreads();
  #pragma unroll 4
  for (int rr = 0; rr < 16; ++rr) {
    const int cc = rr*4 + t4;
    Vt[((size_t)g*kHD + cc)*kM + i0 + c] = vs[c][cc];
  }
}

__global__ __launch_bounds__(256) void prep_s2s_k(
    const u16* __restrict__ qkvU, const float* __restrict__ kenc,
    float* __restrict__ Qs, u16* __restrict__ Kb, u16* __restrict__ Vt)
{
  __shared__ u16 vs[64][66];
  const int g = blockIdx.x >> 3, i0 = (blockIdx.x & 7)*64;   // g = bh*6+view
  const int view = g % kN, bh = g / kN;
  const int h = bh & 3, b = bh >> 2;
  const int c = threadIdx.x & 63, t4 = threadIdx.x >> 6;
  const float sgn = (c & 1) ? 1.f : -1.f;
  #pragma unroll 4
  for (int rr = 0; rr < 16; ++rr) {
    const int il = rr*4 + t4, i = i0 + il;
    const u16* base = qkvU + ((size_t)(kRowsH + (b*kN+view)*kM + i))*768 + h*192;
    const float k = b2f(base[c*3+1]), kp = b2f(base[(c^1)*3+1]);
    const size_t eo = ((size_t)(view*kM + i))*kHD + c;
    const float e0 = kenc[eo], e1 = kenc[kEncSlab + eo];
    Qs[((size_t)g*kM + i)*kHD + c] = b2f(base[c*3]);
    Kb[((size_t)g*kM + i)*kHD + c] = f2b(k*e0 + sgn*kp*e1);
    vs[il][c] = base[c*3+2];
  }
  __syncthreads();
  #pragma unroll 4
  for (int rr = 0; rr < 16; ++rr) {
    const int cc = rr*4 + t4;
    Vt[((size_t)g*kHD + cc)*kM + i0 + c] = vs[c][cc];
  }
}

// cross prep reads combined [12288][768] buffer (cols 256..767 = kv, h*128 + c*2 + {k,v});
// kv half is the OPPOSITE descriptor half (t2 uses kv from s, s2 from t).
__global__ __launch_bounds__(256) void prep_cross_k(
    const u16* __restrict__ qkvC, u16* __restrict__ Kb, u16* __restrict__ Vt)
{
  __shared__ u16 vs[64][66];
  const int g = blockIdx.x >> 3, i0 = (blockIdx.x & 7)*64;
  const int h = g & 3, bn = g >> 2;
  const int src = (bn < 12) ? bn + 12 : bn - 12;
  const int c = threadIdx.x & 63, t4 = threadIdx.x >> 6;
  #pragma unroll 4
  for (int rr = 0; rr < 16; ++rr) {
    const int il = rr*4 + t4, i = i0 + il;
    const u16* base = qkvC + ((size_t)src*kM + i)*768 + 256 + h*128;
    Kb[((size_t)g*kM + i)*kHD + c] = f2b(b2f(base[c*2]) * 0.125f);
    vs[il][c] = base[c*2+1];
  }
  __syncthreads();
  #pragma unroll 4
  for (int rr = 0; rr < 16; ++rr) {
    const int cc = rr*4 + t4;
    Vt[((size_t)g*kHD + cc)*kM + i0 + c] = vs[c][cc];
  }
}

// ---------------------------------------------------------------------------
// Two-pass MFMA attention segment: 256 keys held in registers.
// QK^T (S^T): st[t2][i] on lane (qr,hi) = S[key k0+t2*16+hi*4+i][q-row qr].
// Batched softmax (exact within segment, one rescale between segments), then
// per-32-key redistribution (E/F/G/H mapping, byte-verified in r6) + PV.
// NOTE: the inter-segment rescale guard MUST be wave-uniform (__any): the
// acc entries on a lane belong to q-rows hi*4+j != qr, and the shfl
// broadcasts need all lanes active (r7 bug: per-lane guard -> absmax 2.0).
// ---------------------------------------------------------------------------
__device__ __forceinline__ void attn_seg(
    const u16* __restrict__ Kg, const u16* __restrict__ Vg,
    s16x8 qf0, s16x8 qf1, int k0, int qr, int hi,
    f32x4 acc[4], float& m, float& l, bool first)
{
  const bool subhi = (hi & 1);
  const bool up = (hi >= 2);
  f32x4 st[16];
  #pragma unroll
  for (int t2 = 0; t2 < 16; ++t2) {
    const u16* kp = Kg + ((size_t)(k0 + t2*16 + qr))*kHD + hi*8;
    s16x8 a0 = *(const s16x8*)(kp);
    s16x8 a1 = *(const s16x8*)(kp + 32);
    f32x4 z = {0.f, 0.f, 0.f, 0.f};
    z = __builtin_amdgcn_mfma_f32_16x16x32_bf16(a0, qf0, z, 0, 0, 0);
    z = __builtin_amdgcn_mfma_f32_16x16x32_bf16(a1, qf1, z, 0, 0, 0);
    st[t2] = z;
  }
  // in-lane max tree over 64 scores, then cross-hi reduce
  f32x4 t8[8];
  #pragma unroll
  for (int i = 0; i < 8; ++i) t8[i] = vmax4(st[2*i], st[2*i+1]);
  #pragma unroll
  for (int i = 0; i < 4; ++i) t8[i] = vmax4(t8[i], t8[i+4]);
  t8[0] = vmax4(vmax4(t8[0], t8[1]), vmax4(t8[2], t8[3]));
  float mloc = fmaxf(fmaxf(t8[0][0], t8[0][1]), fmaxf(t8[0][2], t8[0][3]));
  mloc = fmaxf(mloc, __shfl_xor(mloc, 16));
  mloc = fmaxf(mloc, __shfl_xor(mloc, 32));
  if (first) {
    m = mloc;
  } else if (__any(mloc > m)) {          // wave-uniform guard (see NOTE)
    const float mn = fmaxf(m, mloc);
    const float r = exp2f((m - mn)*kL2E);  // ==1 for rows that didn't grow
    m = mn;
    l *= r;
    const float rr0 = __shfl(r, hi*4+0), rr1 = __shfl(r, hi*4+1);
    const float rr2 = __shfl(r, hi*4+2), rr3 = __shfl(r, hi*4+3);
    #pragma unroll
    for (int db = 0; db < 4; ++db) {
      acc[db][0] *= rr0; acc[db][1] *= rr1; acc[db][2] *= rr2; acc[db][3] *= rr3;
    }
  }
  // exp in place + sum
  const float mk = m * kL2E;
  #pragma unroll
  for (int t2 = 0; t2 < 16; ++t2)
    #pragma unroll
    for (int i = 0; i < 4; ++i)
      st[t2][i] = exp2f(st[t2][i]*kL2E - mk);
  {
    f32x4 s8[8];
    #pragma unroll
    for (int i = 0; i < 8; ++i) s8[i] = st[2*i] + st[2*i+1];
    #pragma unroll
    for (int i = 0; i < 4; ++i) s8[i] = s8[i] + s8[i+4];
    f32x4 s1 = (s8[0] + s8[1]) + (s8[2] + s8[3]);
    l += (s1[0] + s1[1]) + (s1[2] + s1[3]);
  }
  // redistribute P + PV per 32-key sub-chunk
  #pragma unroll
  for (int j = 0; j < 8; ++j) {
    const unsigned c00 = pk2(st[2*j][0],   st[2*j][1]);
    const unsigned c01 = pk2(st[2*j][2],   st[2*j][3]);
    const unsigned c10 = pk2(st[2*j+1][0], st[2*j+1][1]);
    const unsigned c11 = pk2(st[2*j+1][2], st[2*j+1][3]);
    const unsigned c00x = __shfl_xor((int)c00, 32), c10x = __shfl_xor((int)c10, 32);
    const unsigned c01x = __shfl_xor((int)c01, 32), c11x = __shfl_xor((int)c11, 32);
    const unsigned E = up ? c10x : c00, F = up ? c10 : c00x;
    const unsigned G = up ? c11x : c01, H = up ? c11 : c01x;
    const unsigned Ex = __shfl_xor((int)E, 16), Fx = __shfl_xor((int)F, 16);
    const unsigned Gx = __shfl_xor((int)G, 16), Hx = __shfl_xor((int)H, 16);
    union { unsigned w[4]; s16x8 v; } pa;
    pa.w[0] = subhi ? Fx : E;
    pa.w[1] = subhi ? Hx : G;
    pa.w[2] = subhi ? F  : Ex;
    pa.w[3] = subhi ? H  : Gx;
    #pragma unroll
    for (int db = 0; db < 4; ++db) {
      const u16* vp = Vg + ((size_t)(db*16 + qr))*kM + k0 + j*32 + hi*8;
      const s16x8 vf = *(const s16x8*)(vp);
      acc[db] = __builtin_amdgcn_mfma_f32_16x16x32_bf16(pa.v, vf, acc[db], 0, 0, 0);
    }
  }
}

__device__ __forceinline__ void attn_512(
    const u16* __restrict__ Kg, const u16* __restrict__ Vg,
    s16x8 qf0, s16x8 qf1, int qr, int hi, f32x4 acc[4], float& m, float& l)
{
  attn_seg(Kg, Vg, qf0, qf1, 0,   qr, hi, acc, m, l, true);
  attn_seg(Kg, Vg, qf0, qf1, 256, qr, hi, acc, m, l, false);
}

// self (CROSSQ=0: Qb [96g][512][64] prescaled) / cross (CROSSQ=1: combined
// [12288][768], q in cols 0..255, K prescaled instead)
template<int CROSSQ>
__global__ __launch_bounds__(256) void attn_mm_k(
    const u16* __restrict__ Qb, const u16* __restrict__ Kb,
    const u16* __restrict__ Vt, u16* __restrict__ ctx)
{
  const int w = threadIdx.x >> 6, lane = threadIdx.x & 63;
  const int bij = (blockIdx.x & 7)*96 + (blockIdx.x >> 3);   // XCD-bijective, 768
  const int g = bij >> 3, qblk = bij & 7;
  const int h = g & 3, bn = g >> 2;
  const int q0 = qblk*64 + w*16;
  const int qr = lane & 15, hi = lane >> 4;

  s16x8 qf0, qf1;
  if (CROSSQ) {
    const u16* qp = Qb + ((size_t)(bn*kM + q0 + qr))*768 + h*kHD + hi*8;
    qf0 = *(const s16x8*)(qp); qf1 = *(const s16x8*)(qp + 32);
  } else {
    const u16* qp = Qb + ((size_t)g*kM + q0 + qr)*kHD + hi*8;
    qf0 = *(const s16x8*)(qp); qf1 = *(const s16x8*)(qp + 32);
  }

  const u16* Kg = Kb + (size_t)g*kM*kHD;
  const u16* Vg = Vt + (size_t)g*kHD*kM;
  f32x4 acc[4] = {};
  float m = -1e30f, l = 0.f;
  attn_512(Kg, Vg, qf0, qf1, qr, hi, acc, m, l);

  l += __shfl_xor(l, 16); l += __shfl_xor(l, 32);
  const float li = 1.f/l;
  const float l0 = __shfl(li, hi*4+0), l1 = __shfl(li, hi*4+1);
  const float l2 = __shfl(li, hi*4+2), l3 = __shfl(li, hi*4+3);
  #pragma unroll
  for (int db = 0; db < 4; ++db) {
    const size_t base = ((size_t)(bn*kM + q0 + hi*4))*kD + h*kHD + db*16 + qr;
    ctx[base + 0*kD] = f2b(acc[db][0]*l0);
    ctx[base + 1*kD] = f2b(acc[db][1]*l1);
    ctx[base + 2*kD] = f2b(acc[db][2]*l2);
    ctx[base + 3*kD] = f2b(acc[db][3]*l3);
  }
}

__device__ __forceinline__ void rope4(const f32x4 x, const f32x4 e0, const f32x4 e1, float o[4])
{
  o[0] = x[0]*e0[0] - x[1]*e1[0];
  o[1] = x[1]*e0[1] + x[0]*e1[1];
  o[2] = x[2]*e0[2] - x[3]*e1[2];
  o[3] = x[3]*e0[3] + x[2]*e1[3];
}

// s2s: block = (bh, col, qblk, split); split = single (i,j) pair 0..4.
// Writes 0.2-scaled normalized partial (bf16) to ctx5[split].
__global__ __launch_bounds__(256) void attn_s2s_k(
    const float* __restrict__ Qraw, const u16* __restrict__ Kb,
    const u16* __restrict__ Vt, const float* __restrict__ qenc,
    u16* __restrict__ ctx5)
{
  const int w = threadIdx.x >> 6, lane = threadIdx.x & 63;
  const int bij = (blockIdx.x & 7)*240 + (blockIdx.x >> 3);  // 1920; chunk == bh
  const int bh = bij / 240;
  const int rest = bij % 240;
  const int col = rest / 40;
  const int rem = rest % 40;
  const int qblk = rem / 5, split = rem % 5;
  const int q0 = qblk*64 + w*16;
  const int qr = lane & 15, hi = lane >> 4;

  const int e  = split*6 + col;
  const int iv = e/5;
  const int j0 = e%5;
  const int jv = j0 + (j0 >= iv ? 1 : 0);
  s16x8 qf0, qf1;
  {
    const float* qp = Qraw + ((size_t)(bh*kN + jv)*kM + q0 + qr)*kHD + hi*8;
    const float* ep = qenc + ((size_t)(iv*kN + jv))*kHD + hi*8;
    union { u16 u[8]; s16x8 v; } A, B;
    float o[4];
    rope4(*(const f32x4*)(qp),   *(const f32x4*)(ep),   *(const f32x4*)(ep+kQEncSlab), o);
    #pragma unroll
    for (int j = 0; j < 4; ++j) A.u[j] = f2b(o[j]*0.125f);
    rope4(*(const f32x4*)(qp+4), *(const f32x4*)(ep+4), *(const f32x4*)(ep+kQEncSlab+4), o);
    #pragma unroll
    for (int j = 0; j < 4; ++j) A.u[4+j] = f2b(o[j]*0.125f);
    rope4(*(const f32x4*)(qp+32), *(const f32x4*)(ep+32), *(const f32x4*)(ep+kQEncSlab+32), o);
    #pragma unroll
    for (int j = 0; j < 4; ++j) B.u[j] = f2b(o[j]*0.125f);
    rope4(*(const f32x4*)(qp+36), *(const f32x4*)(ep+36), *(const f32x4*)(ep+kQEncSlab+36), o);
    #pragma unroll
    for (int j = 0; j < 4; ++j) B.u[4+j] = f2b(o[j]*0.125f);
    qf0 = A.v; qf1 = B.v;
  }
  const int g2 = bh*kN + iv;
  const u16* Kg = Kb + (size_t)g2*kM*kHD;
  const u16* Vg = Vt + (size_t)g2*kHD*kM;
  f32x4 acc[4] = {};
  float m = -1e30f, l = 0.f;
  attn_512(Kg, Vg, qf0, qf1, qr, hi, acc, m, l);
  l += __shfl_xor(l, 16); l += __shfl_xor(l, 32);
  const float li = 0.2f/l;
  const float l0 = __shfl(li, hi*4+0), l1 = __shfl(li, hi*4+1);
  const float l2 = __shfl(li, hi*4+2), l3 = __shfl(li, hi*4+3);

  const int b = bh >> 2, h = bh & 3;
  u16* outp = ctx5 + (size_t)split*kTOK;
  #pragma unroll
  for (int db = 0; db < 4; ++db) {
    const size_t base = ((size_t)((b*kN + col)*kM + q0 + hi*4))*kD + h*kHD + db*16 + qr;
    outp[base + 0*kD] = f2b(acc[db][0]*l0);
    outp[base + 1*kD] = f2b(acc[db][1]*l1);
    outp[base + 2*kD] = f2b(acc[db][2]*l2);
    outp[base + 3*kD] = f2b(acc[db][3]*l3);
  }
}

__global__ __launch_bounds__(256) void sum5_k(const u16* __restrict__ c5,
                                              u16* __restrict__ outU)
{
  const size_t i4 = ((size_t)blockIdx.x*256 + threadIdx.x)*4;
  float s0=0.f, s1=0.f, s2=0.f, s3=0.f;
  #pragma unroll
  for (int sp = 0; sp < 5; ++sp) {
    uint2 d = *(const uint2*)(c5 + sp*kTOK + i4);
    s0 += b2f((u16)(d.x & 0xffff)); s1 += b2f((u16)(d.x >> 16));
    s2 += b2f((u16)(d.y & 0xffff)); s3 += b2f((u16)(d.y >> 16));
  }
  union { u16 u[4]; uint2 d; } o;
  o.u[0]=f2b(s0); o.u[1]=f2b(s1); o.u[2]=f2b(s2); o.u[3]=f2b(s3);
  *(uint2*)(outU + i4) = o.d;
}

// t2t attention: wave per (b,h,nq,m) — 24576 waves.
__global__ __launch_bounds__(256) void attn_t2t_k(
    const u16* __restrict__ qkvU, u16* __restrict__ ctxU)
{
  const int wid = blockIdx.x*4 + (threadIdx.x >> 6);
  const int lane = threadIdx.x & 63;
  const int m = wid & 511;
  const int t = wid >> 9;
  const int nq = t % kN;
  const int bh = t / kN;
  const int h = bh & 3, b = bh >> 2;
  const u16* pb[kN];
  #pragma unroll
  for (int nk = 0; nk < kN; ++nk)
    pb[nk] = qkvU + ((size_t)(b*kN+nk)*kM + m)*768 + h*192;
  const float qc = b2f(pb[nq][lane*3]);
  float sim[kN];
  #pragma unroll
  for (int nk = 0; nk < kN; ++nk)
    sim[nk] = wred_sum(qc * b2f(pb[nk][lane*3+1])) * 0.125f;
  float mx = sim[0];
  #pragma unroll
  for (int nk = 1; nk < kN; ++nk) mx = fmaxf(mx, sim[nk]);
  float p[kN], s = 0.f;
  #pragma unroll
  for (int nk = 0; nk < kN; ++nk) { p[nk] = expf(sim[nk]-mx); s += p[nk]; }
  const float inv = 1.f/s;
  float o = 0.f;
  #pragma unroll
  for (int nk = 0; nk < kN; ++nk) o = fmaf(p[nk], b2f(pb[nk][lane*3+2]), o);
  ctxU[((size_t)(b*kN+nq)*kM + m)*kD + h*kHD + lane] = f2b(o*inv);
}

// LayerNorm(512) + exact GELU: reads f32, writes bf16 (separate buffer).
__global__ __launch_bounds__(256) void lngelu_k(
    const float* __restrict__ x, u16* __restrict__ y,
    const float* __restrict__ g0, const float* __restrict__ b0,
    const float* __restrict__ g1, const float* __restrict__ b1, int Mh)
{
  const int row = blockIdx.x;
  const int tid = threadIdx.x;
  const float* g = (row < Mh) ? g0 : g1;
  const float* bb = (row < Mh) ? b0 : b1;
  const float* xr = x + (size_t)row*512;
  const float v0 = xr[tid], v1 = xr[tid+256];
  const int w = tid >> 6, lane = tid & 63;
  __shared__ float red[2][4];
  const float s1 = wred_sum(v0+v1);
  const float s2 = wred_sum(v0*v0+v1*v1);
  if (lane == 0){ red[0][w]=s1; red[1][w]=s2; }
  __syncthreads();
  const float mean = (red[0][0]+red[0][1]+red[0][2]+red[0][3]) * (1.f/512.f);
  const float ms   = (red[1][0]+red[1][1]+red[1][2]+red[1][3]) * (1.f/512.f);
  const float rs = rsqrtf(ms - mean*mean + 1e-5f);
  const float y0 = (v0-mean)*rs*g[tid]     + bb[tid];
  const float y1 = (v1-mean)*rs*g[tid+256] + bb[tid+256];
  y[(size_t)row*512 + tid]     = f2b(0.5f*y0*(1.f+erff(y0*0.70710678118654752f)));
  y[(size_t)row*512 + tid+256] = f2b(0.5f*y1*(1.f+erff(y1*0.70710678118654752f)));
}

__global__ void conf_dot_k(const float* __restrict__ tmp, const float* __restrict__ w2,
                           const float* __restrict__ b2, float* __restrict__ out)
{
  const int w = threadIdx.x >> 6, lane = threadIdx.x & 63;
  const int row = blockIdx.x*4 + w;
  const float* t = tmp + (size_t)row*kD;
  float s = 0.f;
  #pragma unroll
  for (int j=0;j<4;++j) s = fmaf(t[lane+j*64], w2[lane+j*64], s);
  s = wred_sum(s);
  if (lane == 0) out[row] = s + b2[0];
}

// ---------------------------------------------------------------------------
extern "C" void kernel_launch(void* const* d_in, const int* in_sizes, int n_in,
                              void* d_out, int out_size, void* d_ws, size_t ws_size,
                              hipStream_t stream)
{
  auto F = [&](int i){ return (const float*)d_in[i]; };
  const float* t_desc = F(0);
  const float* s_desc = F(1);
  const float* t_enc  = F(2);
  const float* s_enc  = F(3);
  const float* q_enc  = F(4);
  const float* k_enc  = F(5);

  // ---- workspace map ----
  char* base = (char*)d_ws;
  float* xts = (float*)base;                     // 12288x256 f32 (xt|xs)
  float* xt = xts;
  float* xs = xts + kTOK;
  char* R1  = base + 2*kTOK*sizeof(float);       // 25.17 MB multi-use
  char* CTX = R1 + 4*kTOK*sizeof(float);         // 6.29 MB
  char* MSG = CTX + 2*kTOK*sizeof(u16);          // 6.29 MB
  u16* Qb16 = (u16*)(MSG + kTOK*sizeof(float));  // 96x512x64
  u16* Kb16 = Qb16 + 2*kTOK;
  u16* Vt16 = Kb16 + 2*kTOK;
  u16* wsW  = Vt16 + 2*kTOK;
  // aliases
  u16*   qkvU  = (u16*)R1;                       // 12288x768
  float* hbuf  = (float*)R1;                     // 12288x512 f32
  u16*   ctx5  = (u16*)R1;                       // 5 x 6144x256 bf16 (s2s partials)
  u16*   ctxU  = (u16*)CTX;                      // 12288x256
  u16*   msgU  = (u16*)MSG;                      // 12288x256
  float* Qs2s  = (float*)MSG;                    // 48x512x64 f32
  float* confb = (float*)MSG;                    // 6144x256 f32
  u16*   yU    = (u16*)CTX;                      // 12288x512 (spans CTX+MSG)

  float* out_t2s2 = (float*)d_out;               // rows 0..12287 (t2|s2)
  float* out_conf = (float*)d_out + 2*kTOK;

  // ---- weight transpose+cast table ----
  WtTable tab;
  int nd = 0, total_tiles = 0;
  size_t woff = 0;
  const u16* wp[18];
  auto addw = [&](int idx, int K, int N){
    u16* dst = wsW + woff;
    tab.d[nd] = { F(idx), dst, K, N, (K>>5)*(N>>5) };
    total_tiles += tab.d[nd].ntiles;
    wp[nd] = dst;
    woff += (size_t)K*N;
    ++nd;
    return nd-1;
  };
  const int W_SA_QKV = addw(6, 256, 768);
  const int W_SA_OUT = addw(8, 256, 256);
  const int W_SA_F1  = addw(10, 512, 512);
  const int W_SA_F2  = addw(14, 512, 256);
  const int W_SS_QKV = addw(16, 256, 768);
  const int W_SS_OUT = addw(18, 256, 256);
  const int W_SS_F1  = addw(20, 512, 512);
  const int W_SS_F2  = addw(24, 512, 256);
  const int W_TT_QKV = addw(26, 256, 768);
  const int W_TT_OUT = addw(28, 256, 256);
  const int W_TT_F1  = addw(30, 512, 512);
  const int W_TT_F2  = addw(34, 512, 256);
  const int W_CA_Q   = addw(36, 256, 256);   // contiguous with W_CA_KV => [768][256]
  const int W_CA_KV  = addw(38, 256, 512);
  const int W_CA_OUT = addw(40, 256, 256);
  const int W_CA_F1  = addw(42, 512, 512);
  const int W_CA_F2  = addw(46, 512, 256);
  const int W_CF_1   = addw(48, 256, 256);
  (void)W_CA_KV;
  wtcast_k<<<total_tiles, 256, 0, stream>>>(tab);

  // mmad launchers (dual row-segment, 12288 rows)
  auto mm_f32_to_b16 = [&](const float* a1a, const float* a1b, int wa, int wb2,
                           const float* ba, const float* bb2, u16* c, int N_, int K_){
    dim3 grid(N_/128, kRows/128);
    mmad_k<false,false,true><<<grid,256,0,stream>>>(a1a, a1b, nullptr, nullptr, K_,
        wp[wa], wp[wb2], ba, bb2, ba, bb2, N_, nullptr, nullptr, c, N_, K_, kRowsH, 0);
  };
  auto mm_b16_to_b16 = [&](const u16* a1a, const u16* a1b, int wa, int wb2,
                           const float* ba, const float* bb2, u16* c, int N_, int K_){
    dim3 grid(N_/128, kRows/128);
    mmad_k<true,false,true><<<grid,256,0,stream>>>(a1a, a1b, nullptr, nullptr, K_,
        wp[wa], wp[wb2], ba, bb2, ba, bb2, N_, nullptr, nullptr, c, N_, K_, kRowsH, 0);
  };
  auto mm_f1 = [&](const float* a1a, const float* a1b, const u16* a2a, const u16* a2b,
                   int wa, int wb2, const float* ba, const float* bb2, float* c){
    dim3 grid(512/128, kRows/128);
    mmad_k<false,true,false><<<grid,256,0,stream>>>(a1a, a1b, a2a, a2b, 256,
        wp[wa], wp[wb2], ba, bb2, ba, bb2, 512, nullptr, nullptr, c, 512, 512, kRowsH, 0);
  };
  auto mm_f2 = [&](const u16* a1a, const u16* a1b, int wa, int wb2,
                   const float* ba, const float* bb2,
                   const float* ra, const float* rb, float* c){
    dim3 grid(256/128, kRows/128);
    mmad_k<true,false,false><<<grid,256,0,stream>>>(a1a, a1b, nullptr, nullptr, 512,
        wp[wa], wp[wb2], ba, bb2, ba, bb2, 256, ra, rb, c, 256, 512, kRowsH, 0);
  };

  // ================= SELF (t || s, shared sa weights) =================
  mm_f32_to_b16(t_desc, s_desc, W_SA_QKV, W_SA_QKV, F(7), F(7), qkvU, 768, 256);
  prep_self_k<<<kGrp*8, 256, 0, stream>>>(qkvU, t_enc, s_enc, Qb16, Kb16, Vt16);
  attn_mm_k<0><<<kGrp*8, 256, 0, stream>>>(Qb16, Kb16, Vt16, ctxU);
  mm_b16_to_b16(ctxU, ctxU + kTOK, W_SA_OUT, W_SA_OUT, F(9), F(9), msgU, 256, 256);
  mm_f1(t_desc, s_desc, msgU, msgU + kTOK, W_SA_F1, W_SA_F1, F(11), F(11), hbuf);
  lngelu_k<<<kRows, 256, 0, stream>>>(hbuf, yU, F(12), F(13), F(12), F(13), kRowsH);
  mm_f2(yU, yU + (size_t)kRowsH*512, W_SA_F2, W_SA_F2, F(15), F(15), t_desc, s_desc, xts);

  // ================= TT (t) || SS (s) =================
  mm_f32_to_b16(xt, xs, W_TT_QKV, W_SS_QKV, F(27), F(17), qkvU, 768, 256);
  prep_s2s_k<<<kGrpH*8, 256, 0, stream>>>(qkvU, k_enc, Qs2s, Kb16, Vt16);
  attn_t2t_k<<<(kB*kH*kN*kM)/4, 256, 0, stream>>>(qkvU, ctxU);
  attn_s2s_k<<<1920, 256, 0, stream>>>(Qs2s, Kb16, Vt16, q_enc, ctx5);
  sum5_k<<<(int)(kTOK/1024), 256, 0, stream>>>(ctx5, ctxU + kTOK);
  mm_b16_to_b16(ctxU, ctxU + kTOK, W_TT_OUT, W_SS_OUT, F(29), F(19), msgU, 256, 256);
  mm_f1(xt, xs, msgU, msgU + kTOK, W_TT_F1, W_SS_F1, F(31), F(21), hbuf);
  lngelu_k<<<kRows, 256, 0, stream>>>(hbuf, yU, F(32), F(33), F(22), F(23), kRowsH);
  mm_f2(yU, yU + (size_t)kRowsH*512, W_TT_F2, W_SS_F2, F(35), F(25), xt, xs, xts);

  // ================= CONF (from xs post-s2s) =================
  {
    dim3 grid(2, kRowsH/128);
    mmad_k<false,false,false><<<grid,256,0,stream>>>(xs, xs, nullptr, nullptr, 256,
        wp[W_CF_1], wp[W_CF_1], F(49), F(49), F(49), F(49), 256,
        nullptr, nullptr, confb, 256, 256, kRowsH, 1);
  }
  conf_dot_k<<<kRowsH/4, 256, 0, stream>>>(confb, F(50), F(51), out_conf);

  // ================= CROSS (merged q+kv GEMM; t2: q=xt,kv=xs || s2: q=xs,kv=xt) ======
  // combined C[12288][768]: cols 0..255 = q, 256..767 = kv (interleaved per head)
  {
    dim3 grid(768/128, kRows/128);
    mmad_k<false,false,true><<<grid,256,0,stream>>>(xt, xs, nullptr, nullptr, 256,
        wp[W_CA_Q], wp[W_CA_Q], F(37), F(37), F(39), F(39), 256,
        nullptr, nullptr, qkvU, 768, 256, kRowsH, 0);
  }
  prep_cross_k<<<kGrp*8, 256, 0, stream>>>(qkvU, Kb16, Vt16);
  attn_mm_k<1><<<kGrp*8, 256, 0, stream>>>(qkvU, Kb16, Vt16, ctxU);
  mm_b16_to_b16(ctxU, ctxU + kTOK, W_CA_OUT, W_CA_OUT, F(41), F(41), msgU, 256, 256);
  mm_f1(xt, xs, msgU, msgU + kTOK, W_CA_F1, W_CA_F1, F(43), F(43), hbuf);
  lngelu_k<<<kRows, 256, 0, stream>>>(hbuf, yU, F(44), F(45), F(44), F(45), kRowsH);
  mm_f2(yU, yU + (size_t)kRowsH*512, W_CA_F2, W_CA_F2, F(47), F(47), xt, xs, out_t2s2);
}

// Round 9
// 523.840 us; speedup vs baseline: 1.1110x; 1.1110x over previous
//
#include <hip/hip_runtime.h>
#include <hip/hip_bf16.h>
#include <math.h>

// Problem constants
constexpr int kD   = 256;   // model dim
constexpr int kH   = 4;     // heads
constexpr int kHD  = 64;    // head dim
constexpr int kB   = 2;
constexpr int kN   = 6;     // views
constexpr int kM   = 512;   // keypoints (M == NS)
constexpr int kRowsH = kB*kN*kM;          // 6144 rows per half (t or s)
constexpr int kRows  = 2*kRowsH;          // 12288 merged rows
constexpr int kGrpH  = kB*kN*kH;          // 48 attention groups per half
constexpr int kGrp   = 2*kGrpH;           // 96 merged groups
constexpr size_t kTOK = (size_t)kRowsH*kD;        // 1,572,864
constexpr size_t kEncSlab = (size_t)kN*kM*kHD;    // 196608
constexpr size_t kQEncSlab = (size_t)kN*kN*kHD;   // 2304
constexpr float kL2E = 1.4426950408889634f;

typedef unsigned short u16;
typedef __attribute__((ext_vector_type(8))) short s16x8;
typedef __attribute__((ext_vector_type(4))) float f32x4;

__device__ __forceinline__ float wred_sum(float v){
  #pragma unroll
  for (int m=32;m>0;m>>=1) v += __shfl_xor(v, m, 64);
  return v;
}
__device__ __forceinline__ u16 f2b(float x){
  union { float f; unsigned u; } a; a.f = x;
  unsigned r = a.u + 0x7fffu + ((a.u >> 16) & 1u);
  return (u16)(r >> 16);
}
__device__ __forceinline__ float b2f(u16 x){
  union { unsigned u; float f; } a; a.u = ((unsigned)x) << 16;
  return a.f;
}
__device__ __forceinline__ unsigned pk2(float lo, float hi){
  union { __hip_bfloat162 h2; unsigned u; } c;
  c.h2 = __float22bfloat162_rn(make_float2(lo, hi));
  return c.u;
}

// ---------------------------------------------------------------------------
// Weight cast into GEMM staging-tile image: for each 128-col x 32-k tile,
// 4096 u16 laid out EXACTLY as the mmad Bs LDS image (XOR swizzle baked in):
//   u16 idx i: ar=i>>5, w8=(i>>3)&3, e=i&7; sw=(ar>>1)&3
//   value = bf16( W[k0 + ((w8^sw)<<3) + e][n0 + ar] )
// Tile order: tile_id = nt*(K/32) + kt  (nt-major).
// ---------------------------------------------------------------------------
struct WtDesc { const float* W; u16* Wt; int K; int N; int ntiles; };
struct WtTable { WtDesc d[18]; };

__global__ __launch_bounds__(256) void wtcast_k(WtTable tab)
{
  int t = blockIdx.x, mi = 0;
  while (t >= tab.d[mi].ntiles) { t -= tab.d[mi].ntiles; ++mi; }
  const float* W = tab.d[mi].W;
  u16* Wt = tab.d[mi].Wt;
  const int K = tab.d[mi].K, N = tab.d[mi].N;
  const int ktn = K >> 5;
  const int nt = t / ktn, kt = t % ktn;
  const int n0 = nt*128, k0 = kt*32;
  u16* dst = Wt + (size_t)t*4096;
  #pragma unroll
  for (int s = 0; s < 2; ++s) {
    const int idx0 = (s*256 + (int)threadIdx.x)*8;
    const int ar = idx0 >> 5;
    const int w8 = (idx0 >> 3) & 3;
    const int sw = (ar >> 1) & 3;
    const int kk = k0 + ((w8 ^ sw) << 3);
    const int n  = n0 + ar;
    union { u16 u[8]; s16x8 v; } o;
    #pragma unroll
    for (int e = 0; e < 8; ++e)
      o.u[e] = f2b(W[(size_t)(kk + e)*N + n]);
    *(s16x8*)(dst + idx0) = o.v;
  }
}

// ---------------------------------------------------------------------------
// bf16 MFMA GEMM, dual row-segment (rows<Mh: seg a, else seg b) and dual
// col-segment bias (cols<Ns: bias, else bias2). B staged via async
// global_load_lds from pre-tiled Wt (swizzle baked into the tile image).
// XCD-bijective block swizzle on the flattened grid.
// ---------------------------------------------------------------------------
template<bool A1B, bool A2B, bool CB>
__global__ __launch_bounds__(256) void mmad_k(
    const void* __restrict__ A1a, const void* __restrict__ A1b,
    const void* __restrict__ A2a, const void* __restrict__ A2b, int K1,
    const u16* __restrict__ Wa, const u16* __restrict__ Wb,
    const float* __restrict__ bia, const float* __restrict__ bib,
    const float* __restrict__ bi2a, const float* __restrict__ bi2b, int Ns,
    const float* __restrict__ Ra, const float* __restrict__ Rb,
    void* __restrict__ Cp, int N, int K, int Mh, int doRelu)
{
  __shared__ u16 As[128*32];
  __shared__ u16 Bs[128*32];
  const int tid = threadIdx.x;
  const int lane = tid & 63, w = tid >> 6;
  // XCD swizzle (all grids have total blocks % 8 == 0)
  const int gx = gridDim.x;
  const int nblk = gx * gridDim.y;
  int flat = blockIdx.y*gx + blockIdx.x;
  if (!(nblk & 7)) flat = (flat & 7)*(nblk >> 3) + (flat >> 3);
  const int bxx = flat % gx, byy = flat / gx;
  const int row0 = byy*128, col0 = bxx*128;
  const bool sec = (row0 >= Mh);
  const int lr0 = sec ? row0 - Mh : row0;
  const void* A1 = sec ? A1b : A1a;
  const void* A2 = sec ? A2b : A2a;
  const u16* Wt  = sec ? Wb : Wa;
  const float* bias  = sec ? bib : bia;
  const float* bias2 = sec ? bi2b : bi2a;
  const float* R = sec ? Rb : Ra;
  const int wr = (w >> 1)*64, wc = (w & 1)*64;
  const int ar = tid >> 1, ah = tid & 1;
  const int K2 = K - K1;
  const int ktn = K >> 5;
  f32x4 acc[4][4] = {};

  for (int kt = 0; kt < K; kt += 32) {
    // ---- B: async global->LDS, tile image already swizzled ----
    {
      const u16* wtile = Wt + ((size_t)((col0 >> 7)*ktn + (kt >> 5)))*4096;
      #pragma unroll
      for (int s = 0; s < 2; ++s) {
        const u16* srcp = wtile + (size_t)(s*256 + tid)*8;
        __builtin_amdgcn_global_load_lds(
            (const __attribute__((address_space(1))) void*)srcp,
            (__attribute__((address_space(3))) void*)((char*)Bs + s*4096 + w*1024),
            16, 0, 0);
      }
    }
    // ---- A: register staging (f32->bf16 convert or bf16 copy) ----
    const int kk = kt + ah*16;
    union { u16 u[16]; s16x8 v[2]; } tmp;
    if (kk < K1) {
      if constexpr (A1B) {
        const u16* ap = (const u16*)A1 + (size_t)(lr0+ar)*K1 + kk;
        tmp.v[0] = *(const s16x8*)ap; tmp.v[1] = *(const s16x8*)(ap+8);
      } else {
        const float* ap = (const float*)A1 + (size_t)(lr0+ar)*K1 + kk;
        #pragma unroll
        for (int i = 0; i < 16; i += 4) {
          f32x4 v4 = *(const f32x4*)(ap + i);
          tmp.u[i+0]=f2b(v4.x); tmp.u[i+1]=f2b(v4.y); tmp.u[i+2]=f2b(v4.z); tmp.u[i+3]=f2b(v4.w);
        }
      }
    } else {
      if constexpr (A2B) {
        const u16* ap = (const u16*)A2 + (size_t)(lr0+ar)*K2 + (kk - K1);
        tmp.v[0] = *(const s16x8*)ap; tmp.v[1] = *(const s16x8*)(ap+8);
      } else {
        const float* ap = (const float*)A2 + (size_t)(lr0+ar)*K2 + (kk - K1);
        #pragma unroll
        for (int i = 0; i < 16; i += 4) {
          f32x4 v4 = *(const f32x4*)(ap + i);
          tmp.u[i+0]=f2b(v4.x); tmp.u[i+1]=f2b(v4.y); tmp.u[i+2]=f2b(v4.z); tmp.u[i+3]=f2b(v4.w);
        }
      }
    }
    const int sw = (ar >> 1) & 3;
    *(s16x8*)(&As[ar*32 + ((ah*2+0)^sw)*8]) = tmp.v[0];
    *(s16x8*)(&As[ar*32 + ((ah*2+1)^sw)*8]) = tmp.v[1];
    __syncthreads();
    s16x8 af[4], bfv[4];
    #pragma unroll
    for (int fm = 0; fm < 4; ++fm) {
      const int r = wr + fm*16 + (lane & 15);
      const int g = (lane >> 4) ^ ((r >> 1) & 3);
      af[fm] = *(const s16x8*)(&As[r*32 + g*8]);
    }
    #pragma unroll
    for (int fn = 0; fn < 4; ++fn) {
      const int c = wc + fn*16 + (lane & 15);
      const int g = (lane >> 4) ^ ((c >> 1) & 3);
      bfv[fn] = *(const s16x8*)(&Bs[c*32 + g*8]);
    }
    #pragma unroll
    for (int fm = 0; fm < 4; ++fm)
      #pragma unroll
      for (int fn = 0; fn < 4; ++fn)
        acc[fm][fn] = __builtin_amdgcn_mfma_f32_16x16x32_bf16(af[fm], bfv[fn], acc[fm][fn], 0, 0, 0);
    __syncthreads();
  }

  #pragma unroll
  for (int fm = 0; fm < 4; ++fm) {
    const int ro = wr + fm*16 + (lane >> 4)*4;
    #pragma unroll
    for (int fn = 0; fn < 4; ++fn) {
      const int cc = col0 + wc + fn*16 + (lane & 15);
      const float bv = (cc < Ns) ? bias[cc] : bias2[cc - Ns];
      #pragma unroll
      for (int j = 0; j < 4; ++j) {
        float v = acc[fm][fn][j] + bv;
        if (R) v += R[(size_t)(lr0 + ro + j)*N + cc];
        if (doRelu) v = fmaxf(v, 0.f);
        const size_t idx = (size_t)(row0 + ro + j)*N + cc;
        if constexpr (CB) ((u16*)Cp)[idx] = f2b(v);
        else              ((float*)Cp)[idx] = v;
      }
    }
  }
}

// ---------------------------------------------------------------------------
// Preps (read bf16 qkv/kv): emit bf16 K [g][key][64], bf16 Vt [g][64][key],
// and Q (self: roped+0.125-prescaled bf16; s2s: raw f32; cross: K prescaled).
// ---------------------------------------------------------------------------
__global__ __launch_bounds__(256) void prep_self_k(
    const u16* __restrict__ qkvU, const float* __restrict__ t_enc,
    const float* __restrict__ s_enc,
    u16* __restrict__ Qb, u16* __restrict__ Kb, u16* __restrict__ Vt)
{
  __shared__ u16 vs[64][66];
  const int g = blockIdx.x >> 3, i0 = (blockIdx.x & 7)*64;
  const int h = g & 3, bn = g >> 2;                 // bn 0..23 (t:0-11, s:12-23)
  const float* enc = (bn < 12) ? t_enc : s_enc;
  const int n = (bn < 12 ? bn : bn - 12) % kN;
  const int c = threadIdx.x & 63, t4 = threadIdx.x >> 6;
  const float sgn = (c & 1) ? 1.f : -1.f;
  #pragma unroll 4
  for (int rr = 0; rr < 16; ++rr) {
    const int il = rr*4 + t4, i = i0 + il;
    const u16* base = qkvU + ((size_t)bn*kM + i)*768 + h*192;
    const float q = b2f(base[c*3]), k = b2f(base[c*3+1]);
    const float qp = b2f(base[(c^1)*3]), kp = b2f(base[(c^1)*3+1]);
    const size_t eo = ((size_t)(n*kM + i))*kHD + c;
    const float e0 = enc[eo], e1 = enc[kEncSlab + eo];
    Qb[((size_t)g*kM + i)*kHD + c] = f2b((q*e0 + sgn*qp*e1)*0.125f);
    Kb[((size_t)g*kM + i)*kHD + c] = f2b(k*e0 + sgn*kp*e1);
    vs[il][c] = base[c*3+2];
  }
  __syncthreads();
  #pragma unroll 4
  for (int rr = 0; rr < 16; ++rr) {
    const int cc = rr*4 + t4;
    Vt[((size_t)g*kHD + cc)*kM + i0 + c] = vs[c][cc];
  }
}

__global__ __launch_bounds__(256) void prep_s2s_k(
    const u16* __restrict__ qkvU, const float* __restrict__ kenc,
    float* __restrict__ Qs, u16* __restrict__ Kb, u16* __restrict__ Vt)
{
  __shared__ u16 vs[64][66];
  const int g = blockIdx.x >> 3, i0 = (blockIdx.x & 7)*64;   // g = bh*6+view
  const int view = g % kN, bh = g / kN;
  const int h = bh & 3, b = bh >> 2;
  const int c = threadIdx.x & 63, t4 = threadIdx.x >> 6;
  const float sgn = (c & 1) ? 1.f : -1.f;
  #pragma unroll 4
  for (int rr = 0; rr < 16; ++rr) {
    const int il = rr*4 + t4, i = i0 + il;
    const u16* base = qkvU + ((size_t)(kRowsH + (b*kN+view)*kM + i))*768 + h*192;
    const float k = b2f(base[c*3+1]), kp = b2f(base[(c^1)*3+1]);
    const size_t eo = ((size_t)(view*kM + i))*kHD + c;
    const float e0 = kenc[eo], e1 = kenc[kEncSlab + eo];
    Qs[((size_t)g*kM + i)*kHD + c] = b2f(base[c*3]);
    Kb[((size_t)g*kM + i)*kHD + c] = f2b(k*e0 + sgn*kp*e1);
    vs[il][c] = base[c*3+2];
  }
  __syncthreads();
  #pragma unroll 4
  for (int rr = 0; rr < 16; ++rr) {
    const int cc = rr*4 + t4;
    Vt[((size_t)g*kHD + cc)*kM + i0 + c] = vs[c][cc];
  }
}

// cross prep reads combined [12288][768] buffer (cols 256..767 = kv);
// kv half is the OPPOSITE descriptor half (t2 uses kv from s, s2 from t).
__global__ __launch_bounds__(256) void prep_cross_k(
    const u16* __restrict__ qkvC, u16* __restrict__ Kb, u16* __restrict__ Vt)
{
  __shared__ u16 vs[64][66];
  const int g = blockIdx.x >> 3, i0 = (blockIdx.x & 7)*64;
  const int h = g & 3, bn = g >> 2;
  const int src = (bn < 12) ? bn + 12 : bn - 12;
  const int c = threadIdx.x & 63, t4 = threadIdx.x >> 6;
  #pragma unroll 4
  for (int rr = 0; rr < 16; ++rr) {
    const int il = rr*4 + t4, i = i0 + il;
    const u16* base = qkvC + ((size_t)src*kM + i)*768 + 256 + h*128;
    Kb[((size_t)g*kM + i)*kHD + c] = f2b(b2f(base[c*2]) * 0.125f);
    vs[il][c] = base[c*2+1];
  }
  __syncthreads();
  #pragma unroll 4
  for (int rr = 0; rr < 16; ++rr) {
    const int cc = rr*4 + t4;
    Vt[((size_t)g*kHD + cc)*kM + i0 + c] = vs[c][cc];
  }
}

// ---------------------------------------------------------------------------
// Two-pass MFMA attention segment (16 q-rows), used by self/cross.
// NOTE: inter-segment rescale guard MUST be wave-uniform (__any).
// ---------------------------------------------------------------------------
__device__ __forceinline__ f32x4 vmax4(f32x4 a, f32x4 b){
  f32x4 r;
  r[0]=fmaxf(a[0],b[0]); r[1]=fmaxf(a[1],b[1]);
  r[2]=fmaxf(a[2],b[2]); r[3]=fmaxf(a[3],b[3]);
  return r;
}

__device__ __forceinline__ void attn_seg(
    const u16* __restrict__ Kg, const u16* __restrict__ Vg,
    s16x8 qf0, s16x8 qf1, int k0, int qr, int hi,
    f32x4 acc[4], float& m, float& l, bool first)
{
  const bool subhi = (hi & 1);
  const bool up = (hi >= 2);
  f32x4 st[16];
  #pragma unroll
  for (int t2 = 0; t2 < 16; ++t2) {
    const u16* kp = Kg + ((size_t)(k0 + t2*16 + qr))*kHD + hi*8;
    s16x8 a0 = *(const s16x8*)(kp);
    s16x8 a1 = *(const s16x8*)(kp + 32);
    f32x4 z = {0.f, 0.f, 0.f, 0.f};
    z = __builtin_amdgcn_mfma_f32_16x16x32_bf16(a0, qf0, z, 0, 0, 0);
    z = __builtin_amdgcn_mfma_f32_16x16x32_bf16(a1, qf1, z, 0, 0, 0);
    st[t2] = z;
  }
  f32x4 t8[8];
  #pragma unroll
  for (int i = 0; i < 8; ++i) t8[i] = vmax4(st[2*i], st[2*i+1]);
  #pragma unroll
  for (int i = 0; i < 4; ++i) t8[i] = vmax4(t8[i], t8[i+4]);
  t8[0] = vmax4(vmax4(t8[0], t8[1]), vmax4(t8[2], t8[3]));
  float mloc = fmaxf(fmaxf(t8[0][0], t8[0][1]), fmaxf(t8[0][2], t8[0][3]));
  mloc = fmaxf(mloc, __shfl_xor(mloc, 16));
  mloc = fmaxf(mloc, __shfl_xor(mloc, 32));
  if (first) {
    m = mloc;
  } else if (__any(mloc > m)) {
    const float mn = fmaxf(m, mloc);
    const float r = exp2f((m - mn)*kL2E);
    m = mn;
    l *= r;
    const float rr0 = __shfl(r, hi*4+0), rr1 = __shfl(r, hi*4+1);
    const float rr2 = __shfl(r, hi*4+2), rr3 = __shfl(r, hi*4+3);
    #pragma unroll
    for (int db = 0; db < 4; ++db) {
      acc[db][0] *= rr0; acc[db][1] *= rr1; acc[db][2] *= rr2; acc[db][3] *= rr3;
    }
  }
  const float mk = m * kL2E;
  #pragma unroll
  for (int t2 = 0; t2 < 16; ++t2)
    #pragma unroll
    for (int i = 0; i < 4; ++i)
      st[t2][i] = exp2f(st[t2][i]*kL2E - mk);
  {
    f32x4 s8[8];
    #pragma unroll
    for (int i = 0; i < 8; ++i) s8[i] = st[2*i] + st[2*i+1];
    #pragma unroll
    for (int i = 0; i < 4; ++i) s8[i] = s8[i] + s8[i+4];
    f32x4 s1 = (s8[0] + s8[1]) + (s8[2] + s8[3]);
    l += (s1[0] + s1[1]) + (s1[2] + s1[3]);
  }
  #pragma unroll
  for (int j = 0; j < 8; ++j) {
    const unsigned c00 = pk2(st[2*j][0],   st[2*j][1]);
    const unsigned c01 = pk2(st[2*j][2],   st[2*j][3]);
    const unsigned c10 = pk2(st[2*j+1][0], st[2*j+1][1]);
    const unsigned c11 = pk2(st[2*j+1][2], st[2*j+1][3]);
    const unsigned c00x = __shfl_xor((int)c00, 32), c10x = __shfl_xor((int)c10, 32);
    const unsigned c01x = __shfl_xor((int)c01, 32), c11x = __shfl_xor((int)c11, 32);
    const unsigned E = up ? c10x : c00, F = up ? c10 : c00x;
    const unsigned G = up ? c11x : c01, H = up ? c11 : c01x;
    const unsigned Ex = __shfl_xor((int)E, 16), Fx = __shfl_xor((int)F, 16);
    const unsigned Gx = __shfl_xor((int)G, 16), Hx = __shfl_xor((int)H, 16);
    union { unsigned w[4]; s16x8 v; } pa;
    pa.w[0] = subhi ? Fx : E;
    pa.w[1] = subhi ? Hx : G;
    pa.w[2] = subhi ? F  : Ex;
    pa.w[3] = subhi ? H  : Gx;
    #pragma unroll
    for (int db = 0; db < 4; ++db) {
      const u16* vp = Vg + ((size_t)(db*16 + qr))*kM + k0 + j*32 + hi*8;
      const s16x8 vf = *(const s16x8*)(vp);
      acc[db] = __builtin_amdgcn_mfma_f32_16x16x32_bf16(pa.v, vf, acc[db], 0, 0, 0);
    }
  }
}

__device__ __forceinline__ void attn_512(
    const u16* __restrict__ Kg, const u16* __restrict__ Vg,
    s16x8 qf0, s16x8 qf1, int qr, int hi, f32x4 acc[4], float& m, float& l)
{
  attn_seg(Kg, Vg, qf0, qf1, 0,   qr, hi, acc, m, l, true);
  attn_seg(Kg, Vg, qf0, qf1, 256, qr, hi, acc, m, l, false);
}

// self (CROSSQ=0: Qb [96g][512][64] prescaled) / cross (CROSSQ=1: combined
// [12288][768], q in cols 0..255, K prescaled instead)
template<int CROSSQ>
__global__ __launch_bounds__(256) void attn_mm_k(
    const u16* __restrict__ Qb, const u16* __restrict__ Kb,
    const u16* __restrict__ Vt, u16* __restrict__ ctx)
{
  const int w = threadIdx.x >> 6, lane = threadIdx.x & 63;
  const int bij = (blockIdx.x & 7)*96 + (blockIdx.x >> 3);   // XCD-bijective, 768
  const int g = bij >> 3, qblk = bij & 7;
  const int h = g & 3, bn = g >> 2;
  const int q0 = qblk*64 + w*16;
  const int qr = lane & 15, hi = lane >> 4;

  s16x8 qf0, qf1;
  if (CROSSQ) {
    const u16* qp = Qb + ((size_t)(bn*kM + q0 + qr))*768 + h*kHD + hi*8;
    qf0 = *(const s16x8*)(qp); qf1 = *(const s16x8*)(qp + 32);
  } else {
    const u16* qp = Qb + ((size_t)g*kM + q0 + qr)*kHD + hi*8;
    qf0 = *(const s16x8*)(qp); qf1 = *(const s16x8*)(qp + 32);
  }

  const u16* Kg = Kb + (size_t)g*kM*kHD;
  const u16* Vg = Vt + (size_t)g*kHD*kM;
  f32x4 acc[4] = {};
  float m = -1e30f, l = 0.f;
  attn_512(Kg, Vg, qf0, qf1, qr, hi, acc, m, l);

  l += __shfl_xor(l, 16); l += __shfl_xor(l, 32);
  const float li = 1.f/l;
  const float l0 = __shfl(li, hi*4+0), l1 = __shfl(li, hi*4+1);
  const float l2 = __shfl(li, hi*4+2), l3 = __shfl(li, hi*4+3);
  #pragma unroll
  for (int db = 0; db < 4; ++db) {
    const size_t base = ((size_t)(bn*kM + q0 + hi*4))*kD + h*kHD + db*16 + qr;
    ctx[base + 0*kD] = f2b(acc[db][0]*l0);
    ctx[base + 1*kD] = f2b(acc[db][1]*l1);
    ctx[base + 2*kD] = f2b(acc[db][2]*l2);
    ctx[base + 3*kD] = f2b(acc[db][3]*l3);
  }
}

__device__ __forceinline__ void rope4(const f32x4 x, const f32x4 e0, const f32x4 e1, float o[4])
{
  o[0] = x[0]*e0[0] - x[1]*e1[0];
  o[1] = x[1]*e0[1] + x[0]*e1[1];
  o[2] = x[2]*e0[2] - x[3]*e1[2];
  o[3] = x[3]*e0[3] + x[2]*e1[3];
}

// ---------------------------------------------------------------------------
// s2s: 32 q-rows per wave (2 fragments sharing all K/V loads), online
// softmax + defer-max (round-6 proven core, duplicated per fragment).
// block = (bh, col, qblk(of 128 rows), split); 960 blocks, bh == XCD chunk.
// ---------------------------------------------------------------------------
__global__ __launch_bounds__(256) void attn_s2s_k(
    const float* __restrict__ Qraw, const u16* __restrict__ Kb,
    const u16* __restrict__ Vt, const float* __restrict__ qenc,
    u16* __restrict__ ctx5)
{
  const int w = threadIdx.x >> 6, lane = threadIdx.x & 63;
  const int bij = (blockIdx.x & 7)*120 + (blockIdx.x >> 3);  // 960
  const int bh = bij / 120;
  const int rest = bij % 120;
  const int col = rest / 20;
  const int rem = rest % 20;
  const int qblk = rem / 5, split = rem % 5;
  const int q0 = qblk*128 + w*32;
  const int qr = lane & 15, hi = lane >> 4;
  const bool subhi = (hi & 1), up = (hi >= 2);

  const int e  = split*6 + col;
  const int iv = e/5;
  const int j0 = e%5;
  const int jv = j0 + (j0 >= iv ? 1 : 0);

  s16x8 qf0[2], qf1[2];
  #pragma unroll
  for (int f = 0; f < 2; ++f) {
    const float* qp = Qraw + ((size_t)(bh*kN + jv)*kM + q0 + f*16 + qr)*kHD + hi*8;
    const float* ep = qenc + ((size_t)(iv*kN + jv))*kHD + hi*8;
    union { u16 u[8]; s16x8 v; } A, B;
    float o[4];
    rope4(*(const f32x4*)(qp),   *(const f32x4*)(ep),   *(const f32x4*)(ep+kQEncSlab), o);
    #pragma unroll
    for (int j = 0; j < 4; ++j) A.u[j] = f2b(o[j]*0.125f);
    rope4(*(const f32x4*)(qp+4), *(const f32x4*)(ep+4), *(const f32x4*)(ep+kQEncSlab+4), o);
    #pragma unroll
    for (int j = 0; j < 4; ++j) A.u[4+j] = f2b(o[j]*0.125f);
    rope4(*(const f32x4*)(qp+32), *(const f32x4*)(ep+32), *(const f32x4*)(ep+kQEncSlab+32), o);
    #pragma unroll
    for (int j = 0; j < 4; ++j) B.u[j] = f2b(o[j]*0.125f);
    rope4(*(const f32x4*)(qp+36), *(const f32x4*)(ep+36), *(const f32x4*)(ep+kQEncSlab+36), o);
    #pragma unroll
    for (int j = 0; j < 4; ++j) B.u[4+j] = f2b(o[j]*0.125f);
    qf0[f] = A.v; qf1[f] = B.v;
  }

  const int g2 = bh*kN + iv;
  const u16* Kg = Kb + (size_t)g2*kM*kHD;
  const u16* Vg = Vt + (size_t)g2*kHD*kM;
  f32x4 acc[2][4] = {};
  float m[2] = {-1e30f, -1e30f}, l[2] = {0.f, 0.f};

  for (int kc = 0; kc < 16; ++kc) {
    const int k0 = kc*32;
    s16x8 a0[2], a1[2];
    #pragma unroll
    for (int t = 0; t < 2; ++t) {
      const u16* kp = Kg + ((size_t)(k0 + t*16 + qr))*kHD + hi*8;
      a0[t] = *(const s16x8*)(kp);
      a1[t] = *(const s16x8*)(kp + 32);
    }
    s16x8 pa[2];
    #pragma unroll
    for (int f = 0; f < 2; ++f) {
      f32x4 st[2];
      #pragma unroll
      for (int t = 0; t < 2; ++t) {
        f32x4 z = {0.f, 0.f, 0.f, 0.f};
        z = __builtin_amdgcn_mfma_f32_16x16x32_bf16(a0[t], qf0[f], z, 0, 0, 0);
        z = __builtin_amdgcn_mfma_f32_16x16x32_bf16(a1[t], qf1[f], z, 0, 0, 0);
        st[t] = z;
      }
      float mloc = fmaxf(fmaxf(fmaxf(st[0][0], st[0][1]), fmaxf(st[0][2], st[0][3])),
                         fmaxf(fmaxf(st[1][0], st[1][1]), fmaxf(st[1][2], st[1][3])));
      mloc = fmaxf(mloc, __shfl_xor(mloc, 16));
      mloc = fmaxf(mloc, __shfl_xor(mloc, 32));
      if (!__all(mloc - m[f] <= 8.f)) {
        const float mn = fmaxf(m[f], mloc);
        const float r = exp2f((m[f] - mn)*kL2E);
        m[f] = mn;
        l[f] *= r;
        const float rr0 = __shfl(r, hi*4+0), rr1 = __shfl(r, hi*4+1);
        const float rr2 = __shfl(r, hi*4+2), rr3 = __shfl(r, hi*4+3);
        #pragma unroll
        for (int db = 0; db < 4; ++db) {
          acc[f][db][0] *= rr0; acc[f][db][1] *= rr1;
          acc[f][db][2] *= rr2; acc[f][db][3] *= rr3;
        }
      }
      float p[8], ls = 0.f;
      #pragma unroll
      for (int t = 0; t < 2; ++t)
        #pragma unroll
        for (int j = 0; j < 4; ++j) {
          const float pv = exp2f((st[t][j] - m[f])*kL2E);
          p[t*4+j] = pv; ls += pv;
        }
      l[f] += ls;
      const unsigned c00 = pk2(p[0], p[1]);
      const unsigned c01 = pk2(p[2], p[3]);
      const unsigned c10 = pk2(p[4], p[5]);
      const unsigned c11 = pk2(p[6], p[7]);
      const unsigned c00x = __shfl_xor((int)c00, 32), c10x = __shfl_xor((int)c10, 32);
      const unsigned c01x = __shfl_xor((int)c01, 32), c11x = __shfl_xor((int)c11, 32);
      const unsigned E = up ? c10x : c00, F = up ? c10 : c00x;
      const unsigned G = up ? c11x : c01, H = up ? c11 : c01x;
      const unsigned Ex = __shfl_xor((int)E, 16), Fx = __shfl_xor((int)F, 16);
      const unsigned Gx = __shfl_xor((int)G, 16), Hx = __shfl_xor((int)H, 16);
      union { unsigned w[4]; s16x8 v; } pw;
      pw.w[0] = subhi ? Fx : E;
      pw.w[1] = subhi ? Hx : G;
      pw.w[2] = subhi ? F  : Ex;
      pw.w[3] = subhi ? H  : Gx;
      pa[f] = pw.v;
    }
    #pragma unroll
    for (int db = 0; db < 4; ++db) {
      const u16* vp = Vg + ((size_t)(db*16 + qr))*kM + k0 + hi*8;
      const s16x8 vf = *(const s16x8*)(vp);
      acc[0][db] = __builtin_amdgcn_mfma_f32_16x16x32_bf16(pa[0], vf, acc[0][db], 0, 0, 0);
      acc[1][db] = __builtin_amdgcn_mfma_f32_16x16x32_bf16(pa[1], vf, acc[1][db], 0, 0, 0);
    }
  }

  const int b = bh >> 2, h = bh & 3;
  u16* outp = ctx5 + (size_t)split*kTOK;
  #pragma unroll
  for (int f = 0; f < 2; ++f) {
    float lf = l[f];
    lf += __shfl_xor(lf, 16); lf += __shfl_xor(lf, 32);
    const float li = 0.2f/lf;
    const float l0 = __shfl(li, hi*4+0), l1 = __shfl(li, hi*4+1);
    const float l2 = __shfl(li, hi*4+2), l3 = __shfl(li, hi*4+3);
    #pragma unroll
    for (int db = 0; db < 4; ++db) {
      const size_t base = ((size_t)((b*kN + col)*kM + q0 + f*16 + hi*4))*kD + h*kHD + db*16 + qr;
      outp[base + 0*kD] = f2b(acc[f][db][0]*l0);
      outp[base + 1*kD] = f2b(acc[f][db][1]*l1);
      outp[base + 2*kD] = f2b(acc[f][db][2]*l2);
      outp[base + 3*kD] = f2b(acc[f][db][3]*l3);
    }
  }
}

__global__ __launch_bounds__(256) void sum5_k(const u16* __restrict__ c5,
                                              u16* __restrict__ outU)
{
  const size_t i4 = ((size_t)blockIdx.x*256 + threadIdx.x)*4;
  float s0=0.f, s1=0.f, s2=0.f, s3=0.f;
  #pragma unroll
  for (int sp = 0; sp < 5; ++sp) {
    uint2 d = *(const uint2*)(c5 + sp*kTOK + i4);
    s0 += b2f((u16)(d.x & 0xffff)); s1 += b2f((u16)(d.x >> 16));
    s2 += b2f((u16)(d.y & 0xffff)); s3 += b2f((u16)(d.y >> 16));
  }
  union { u16 u[4]; uint2 d; } o;
  o.u[0]=f2b(s0); o.u[1]=f2b(s1); o.u[2]=f2b(s2); o.u[3]=f2b(s3);
  *(uint2*)(outU + i4) = o.d;
}

// t2t attention: wave per (b,h,nq,m) — 24576 waves.
__global__ __launch_bounds__(256) void attn_t2t_k(
    const u16* __restrict__ qkvU, u16* __restrict__ ctxU)
{
  const int wid = blockIdx.x*4 + (threadIdx.x >> 6);
  const int lane = threadIdx.x & 63;
  const int m = wid & 511;
  const int t = wid >> 9;
  const int nq = t % kN;
  const int bh = t / kN;
  const int h = bh & 3, b = bh >> 2;
  const u16* pb[kN];
  #pragma unroll
  for (int nk = 0; nk < kN; ++nk)
    pb[nk] = qkvU + ((size_t)(b*kN+nk)*kM + m)*768 + h*192;
  const float qc = b2f(pb[nq][lane*3]);
  float sim[kN];
  #pragma unroll
  for (int nk = 0; nk < kN; ++nk)
    sim[nk] = wred_sum(qc * b2f(pb[nk][lane*3+1])) * 0.125f;
  float mx = sim[0];
  #pragma unroll
  for (int nk = 1; nk < kN; ++nk) mx = fmaxf(mx, sim[nk]);
  float p[kN], s = 0.f;
  #pragma unroll
  for (int nk = 0; nk < kN; ++nk) { p[nk] = expf(sim[nk]-mx); s += p[nk]; }
  const float inv = 1.f/s;
  float o = 0.f;
  #pragma unroll
  for (int nk = 0; nk < kN; ++nk) o = fmaf(p[nk], b2f(pb[nk][lane*3+2]), o);
  ctxU[((size_t)(b*kN+nq)*kM + m)*kD + h*kHD + lane] = f2b(o*inv);
}

// LayerNorm(512) + exact GELU: reads f32, writes bf16 (separate buffer).
__global__ __launch_bounds__(256) void lngelu_k(
    const float* __restrict__ x, u16* __restrict__ y,
    const float* __restrict__ g0, const float* __restrict__ b0,
    const float* __restrict__ g1, const float* __restrict__ b1, int Mh)
{
  const int row = blockIdx.x;
  const int tid = threadIdx.x;
  const float* g = (row < Mh) ? g0 : g1;
  const float* bb = (row < Mh) ? b0 : b1;
  const float* xr = x + (size_t)row*512;
  const float v0 = xr[tid], v1 = xr[tid+256];
  const int w = tid >> 6, lane = tid & 63;
  __shared__ float red[2][4];
  const float s1 = wred_sum(v0+v1);
  const float s2 = wred_sum(v0*v0+v1*v1);
  if (lane == 0){ red[0][w]=s1; red[1][w]=s2; }
  __syncthreads();
  const float mean = (red[0][0]+red[0][1]+red[0][2]+red[0][3]) * (1.f/512.f);
  const float ms   = (red[1][0]+red[1][1]+red[1][2]+red[1][3]) * (1.f/512.f);
  const float rs = rsqrtf(ms - mean*mean + 1e-5f);
  const float y0 = (v0-mean)*rs*g[tid]     + bb[tid];
  const float y1 = (v1-mean)*rs*g[tid+256] + bb[tid+256];
  y[(size_t)row*512 + tid]     = f2b(0.5f*y0*(1.f+erff(y0*0.70710678118654752f)));
  y[(size_t)row*512 + tid+256] = f2b(0.5f*y1*(1.f+erff(y1*0.70710678118654752f)));
}

__global__ void conf_dot_k(const float* __restrict__ tmp, const float* __restrict__ w2,
                           const float* __restrict__ b2, float* __restrict__ out)
{
  const int w = threadIdx.x >> 6, lane = threadIdx.x & 63;
  const int row = blockIdx.x*4 + w;
  const float* t = tmp + (size_t)row*kD;
  float s = 0.f;
  #pragma unroll
  for (int j=0;j<4;++j) s = fmaf(t[lane+j*64], w2[lane+j*64], s);
  s = wred_sum(s);
  if (lane == 0) out[row] = s + b2[0];
}

// ---------------------------------------------------------------------------
extern "C" void kernel_launch(void* const* d_in, const int* in_sizes, int n_in,
                              void* d_out, int out_size, void* d_ws, size_t ws_size,
                              hipStream_t stream)
{
  auto F = [&](int i){ return (const float*)d_in[i]; };
  const float* t_desc = F(0);
  const float* s_desc = F(1);
  const float* t_enc  = F(2);
  const float* s_enc  = F(3);
  const float* q_enc  = F(4);
  const float* k_enc  = F(5);

  // ---- workspace map ----
  char* base = (char*)d_ws;
  float* xts = (float*)base;                     // 12288x256 f32 (xt|xs)
  float* xt = xts;
  float* xs = xts + kTOK;
  char* R1  = base + 2*kTOK*sizeof(float);       // 25.17 MB multi-use
  char* CTX = R1 + 4*kTOK*sizeof(float);         // 6.29 MB
  char* MSG = CTX + 2*kTOK*sizeof(u16);          // 6.29 MB
  u16* Qb16 = (u16*)(MSG + kTOK*sizeof(float));  // 96x512x64
  u16* Kb16 = Qb16 + 2*kTOK;
  u16* Vt16 = Kb16 + 2*kTOK;
  u16* wsW  = Vt16 + 2*kTOK;
  // aliases
  u16*   qkvU  = (u16*)R1;                       // 12288x768
  float* hbuf  = (float*)R1;                     // 12288x512 f32
  u16*   ctx5  = (u16*)R1;                       // 5 x 6144x256 bf16 (s2s partials)
  u16*   ctxU  = (u16*)CTX;                      // 12288x256
  u16*   msgU  = (u16*)MSG;                      // 12288x256
  float* Qs2s  = (float*)MSG;                    // 48x512x64 f32
  float* confb = (float*)MSG;                    // 6144x256 f32
  u16*   yU    = (u16*)CTX;                      // 12288x512 (spans CTX+MSG)

  float* out_t2s2 = (float*)d_out;               // rows 0..12287 (t2|s2)
  float* out_conf = (float*)d_out + 2*kTOK;

  // ---- weight cast table (tiled Bs-image layout) ----
  WtTable tab;
  int nd = 0, total_tiles = 0;
  size_t woff = 0;
  const u16* wp[18];
  auto addw = [&](int idx, int K, int N){
    u16* dst = wsW + woff;
    tab.d[nd] = { F(idx), dst, K, N, (N>>7)*(K>>5) };
    total_tiles += tab.d[nd].ntiles;
    wp[nd] = dst;
    woff += (size_t)K*N;
    ++nd;
    return nd-1;
  };
  const int W_SA_QKV = addw(6, 256, 768);
  const int W_SA_OUT = addw(8, 256, 256);
  const int W_SA_F1  = addw(10, 512, 512);
  const int W_SA_F2  = addw(14, 512, 256);
  const int W_SS_QKV = addw(16, 256, 768);
  const int W_SS_OUT = addw(18, 256, 256);
  const int W_SS_F1  = addw(20, 512, 512);
  const int W_SS_F2  = addw(24, 512, 256);
  const int W_TT_QKV = addw(26, 256, 768);
  const int W_TT_OUT = addw(28, 256, 256);
  const int W_TT_F1  = addw(30, 512, 512);
  const int W_TT_F2  = addw(34, 512, 256);
  const int W_CA_Q   = addw(36, 256, 256);   // contiguous with W_CA_KV => merged [768] tiles
  const int W_CA_KV  = addw(38, 256, 512);
  const int W_CA_OUT = addw(40, 256, 256);
  const int W_CA_F1  = addw(42, 512, 512);
  const int W_CA_F2  = addw(46, 512, 256);
  const int W_CF_1   = addw(48, 256, 256);
  (void)W_CA_KV;
  wtcast_k<<<total_tiles, 256, 0, stream>>>(tab);

  // mmad launchers (dual row-segment, 12288 rows)
  auto mm_f32_to_b16 = [&](const float* a1a, const float* a1b, int wa, int wb2,
                           const float* ba, const float* bb2, u16* c, int N_, int K_){
    dim3 grid(N_/128, kRows/128);
    mmad_k<false,false,true><<<grid,256,0,stream>>>(a1a, a1b, nullptr, nullptr, K_,
        wp[wa], wp[wb2], ba, bb2, ba, bb2, N_, nullptr, nullptr, c, N_, K_, kRowsH, 0);
  };
  auto mm_b16_to_b16 = [&](const u16* a1a, const u16* a1b, int wa, int wb2,
                           const float* ba, const float* bb2, u16* c, int N_, int K_){
    dim3 grid(N_/128, kRows/128);
    mmad_k<true,false,true><<<grid,256,0,stream>>>(a1a, a1b, nullptr, nullptr, K_,
        wp[wa], wp[wb2], ba, bb2, ba, bb2, N_, nullptr, nullptr, c, N_, K_, kRowsH, 0);
  };
  auto mm_f1 = [&](const float* a1a, const float* a1b, const u16* a2a, const u16* a2b,
                   int wa, int wb2, const float* ba, const float* bb2, float* c){
    dim3 grid(512/128, kRows/128);
    mmad_k<false,true,false><<<grid,256,0,stream>>>(a1a, a1b, a2a, a2b, 256,
        wp[wa], wp[wb2], ba, bb2, ba, bb2, 512, nullptr, nullptr, c, 512, 512, kRowsH, 0);
  };
  auto mm_f2 = [&](const u16* a1a, const u16* a1b, int wa, int wb2,
                   const float* ba, const float* bb2,
                   const float* ra, const float* rb, float* c){
    dim3 grid(256/128, kRows/128);
    mmad_k<true,false,false><<<grid,256,0,stream>>>(a1a, a1b, nullptr, nullptr, 512,
        wp[wa], wp[wb2], ba, bb2, ba, bb2, 256, ra, rb, c, 256, 512, kRowsH, 0);
  };

  // ================= SELF (t || s, shared sa weights) =================
  mm_f32_to_b16(t_desc, s_desc, W_SA_QKV, W_SA_QKV, F(7), F(7), qkvU, 768, 256);
  prep_self_k<<<kGrp*8, 256, 0, stream>>>(qkvU, t_enc, s_enc, Qb16, Kb16, Vt16);
  attn_mm_k<0><<<kGrp*8, 256, 0, stream>>>(Qb16, Kb16, Vt16, ctxU);
  mm_b16_to_b16(ctxU, ctxU + kTOK, W_SA_OUT, W_SA_OUT, F(9), F(9), msgU, 256, 256);
  mm_f1(t_desc, s_desc, msgU, msgU + kTOK, W_SA_F1, W_SA_F1, F(11), F(11), hbuf);
  lngelu_k<<<kRows, 256, 0, stream>>>(hbuf, yU, F(12), F(13), F(12), F(13), kRowsH);
  mm_f2(yU, yU + (size_t)kRowsH*512, W_SA_F2, W_SA_F2, F(15), F(15), t_desc, s_desc, xts);

  // ================= TT (t) || SS (s) =================
  mm_f32_to_b16(xt, xs, W_TT_QKV, W_SS_QKV, F(27), F(17), qkvU, 768, 256);
  prep_s2s_k<<<kGrpH*8, 256, 0, stream>>>(qkvU, k_enc, Qs2s, Kb16, Vt16);
  attn_t2t_k<<<(kB*kH*kN*kM)/4, 256, 0, stream>>>(qkvU, ctxU);
  attn_s2s_k<<<960, 256, 0, stream>>>(Qs2s, Kb16, Vt16, q_enc, ctx5);
  sum5_k<<<(int)(kTOK/1024), 256, 0, stream>>>(ctx5, ctxU + kTOK);
  mm_b16_to_b16(ctxU, ctxU + kTOK, W_TT_OUT, W_SS_OUT, F(29), F(19), msgU, 256, 256);
  mm_f1(xt, xs, msgU, msgU + kTOK, W_TT_F1, W_SS_F1, F(31), F(21), hbuf);
  lngelu_k<<<kRows, 256, 0, stream>>>(hbuf, yU, F(32), F(33), F(22), F(23), kRowsH);
  mm_f2(yU, yU + (size_t)kRowsH*512, W_TT_F2, W_SS_F2, F(35), F(25), xt, xs, xts);

  // ================= CONF (from xs post-s2s) =================
  {
    dim3 grid(2, kRowsH/128);
    mmad_k<false,false,false><<<grid,256,0,stream>>>(xs, xs, nullptr, nullptr, 256,
        wp[W_CF_1], wp[W_CF_1], F(49), F(49), F(49), F(49), 256,
        nullptr, nullptr, confb, 256, 256, kRowsH, 1);
  }
  conf_dot_k<<<kRowsH/4, 256, 0, stream>>>(confb, F(50), F(51), out_conf);

  // ================= CROSS (merged q+kv GEMM; t2: q=xt,kv=xs || s2: q=xs,kv=xt) ======
  {
    dim3 grid(768/128, kRows/128);
    mmad_k<false,false,true><<<grid,256,0,stream>>>(xt, xs, nullptr, nullptr, 256,
        wp[W_CA_Q], wp[W_CA_Q], F(37), F(37), F(39), F(39), 256,
        nullptr, nullptr, qkvU, 768, 256, kRowsH, 0);
  }
  prep_cross_k<<<kGrp*8, 256, 0, stream>>>(qkvU, Kb16, Vt16);
  attn_mm_k<1><<<kGrp*8, 256, 0, stream>>>(qkvU, Kb16, Vt16, ctxU);
  mm_b16_to_b16(ctxU, ctxU + kTOK, W_CA_OUT, W_CA_OUT, F(41), F(41), msgU, 256, 256);
  mm_f1(xt, xs, msgU, msgU + kTOK, W_CA_F1, W_CA_F1, F(43), F(43), hbuf);
  lngelu_k<<<kRows, 256, 0, stream>>>(hbuf, yU, F(44), F(45), F(44), F(45), kRowsH);
  mm_f2(yU, yU + (size_t)kRowsH*512, W_CA_F2, W_CA_F2, F(47), F(47), xt, xs, out_t2s2);
}

// Round 10
// 483.565 us; speedup vs baseline: 1.2035x; 1.0833x over previous
//
#include <hip/hip_runtime.h>
#include <hip/hip_bf16.h>
#include <math.h>

// Problem constants
constexpr int kD   = 256;   // model dim
constexpr int kH   = 4;     // heads
constexpr int kHD  = 64;    // head dim
constexpr int kB   = 2;
constexpr int kN   = 6;     // views
constexpr int kM   = 512;   // keypoints (M == NS)
constexpr int kRowsH = kB*kN*kM;          // 6144 rows per half (t or s)
constexpr int kRows  = 2*kRowsH;          // 12288 merged rows
constexpr int kGrpH  = kB*kN*kH;          // 48 attention groups per half
constexpr int kGrp   = 2*kGrpH;           // 96 merged groups
constexpr size_t kTOK = (size_t)kRowsH*kD;        // 1,572,864
constexpr size_t kEncSlab = (size_t)kN*kM*kHD;    // 196608
constexpr size_t kQEncSlab = (size_t)kN*kN*kHD;   // 2304
constexpr float kL2E = 1.4426950408889634f;

typedef unsigned short u16;
typedef __attribute__((ext_vector_type(8))) short s16x8;
typedef __attribute__((ext_vector_type(4))) float f32x4;

__device__ __forceinline__ float wred_sum(float v){
  #pragma unroll
  for (int m=32;m>0;m>>=1) v += __shfl_xor(v, m, 64);
  return v;
}
__device__ __forceinline__ u16 f2b(float x){
  union { float f; unsigned u; } a; a.f = x;
  unsigned r = a.u + 0x7fffu + ((a.u >> 16) & 1u);
  return (u16)(r >> 16);
}
__device__ __forceinline__ float b2f(u16 x){
  union { unsigned u; float f; } a; a.u = ((unsigned)x) << 16;
  return a.f;
}
__device__ __forceinline__ unsigned pk2(float lo, float hi){
  union { __hip_bfloat162 h2; unsigned u; } c;
  c.h2 = __float22bfloat162_rn(make_float2(lo, hi));
  return c.u;
}

// ---------------------------------------------------------------------------
// FFN out-proj fusion precompute: W'[set] = Wout[set] @ W1_bot[set]  (f32)
// and b1'[set] = b1[set] + bout[set] @ W1_bot[set].
// h = concat(x, msg)@W1 + b1 == concat(x, ctx)@[W1_top; W'] + b1'.
// ---------------------------------------------------------------------------
struct FuseArgs {
  const float* Wout[4]; const float* W1[4];
  const float* bout[4]; const float* b1[4];
  float* Wtmp; float* b1p;
};

__global__ __launch_bounds__(256) void wfuse_k(FuseArgs fa)
{
  const int set = blockIdx.x >> 5;
  const int t = blockIdx.x & 31;
  const int row0 = (t >> 3)*64, col0 = (t & 7)*64;
  const float* A  = fa.Wout[set];            // 256x256
  const float* Bm = fa.W1[set] + 256*512;    // rows 256..511, ld 512
  float* C = fa.Wtmp + (size_t)set*(256*512);
  __shared__ float As[16][65];
  __shared__ float Bs[16][64];
  const int tid = threadIdx.x;
  const int tx = tid & 15, ty = tid >> 4;
  const int ar = tid >> 2, ak = (tid & 3)*4;
  const int wr = tid >> 4, wc = (tid & 15)*4;
  float acc[4][4] = {};
  for (int kt = 0; kt < 256; kt += 16) {
    float4 av = *(const float4*)(A + (size_t)(row0+ar)*256 + kt + ak);
    As[ak+0][ar]=av.x; As[ak+1][ar]=av.y; As[ak+2][ar]=av.z; As[ak+3][ar]=av.w;
    *(float4*)(&Bs[wr][wc]) = *(const float4*)(Bm + (size_t)(kt+wr)*512 + col0 + wc);
    __syncthreads();
    #pragma unroll
    for (int k2=0;k2<16;++k2) {
      float a[4], b[4];
      #pragma unroll
      for (int i=0;i<4;++i) a[i]=As[k2][ty*4+i];
      #pragma unroll
      for (int j=0;j<4;++j) b[j]=Bs[k2][tx*4+j];
      #pragma unroll
      for (int i=0;i<4;++i)
        #pragma unroll
        for (int j=0;j<4;++j) acc[i][j] = fmaf(a[i], b[j], acc[i][j]);
    }
    __syncthreads();
  }
  #pragma unroll
  for (int i=0;i<4;++i)
    #pragma unroll
    for (int j=0;j<4;++j)
      C[(size_t)(row0+ty*4+i)*512 + col0+tx*4+j] = acc[i][j];
}

__global__ __launch_bounds__(256) void biasfuse_k(FuseArgs fa)
{
  const int set = blockIdx.x >> 1;
  const int n = (blockIdx.x & 1)*256 + threadIdx.x;
  const float* W1 = fa.W1[set];
  const float* bo = fa.bout[set];
  float s = fa.b1[set][n];
  for (int k = 0; k < 256; ++k)
    s = fmaf(bo[k], W1[(size_t)(256+k)*512 + n], s);
  fa.b1p[set*512 + n] = s;
}

// ---------------------------------------------------------------------------
// Weight cast into GEMM staging-tile image (Bs LDS image, swizzle baked in).
// Rows >= 256 come from W2 (fused W') when W2 != null.
// ---------------------------------------------------------------------------
struct WtDesc { const float* W; const float* W2; u16* Wt; int K; int N; int ntiles; };
struct WtTable { WtDesc d[18]; };

__global__ __launch_bounds__(256) void wtcast_k(WtTable tab)
{
  int t = blockIdx.x, mi = 0;
  while (t >= tab.d[mi].ntiles) { t -= tab.d[mi].ntiles; ++mi; }
  const float* W = tab.d[mi].W;
  const float* W2 = tab.d[mi].W2;
  u16* Wt = tab.d[mi].Wt;
  const int K = tab.d[mi].K, N = tab.d[mi].N;
  const int ktn = K >> 5;
  const int nt = t / ktn, kt = t % ktn;
  const int n0 = nt*128, k0 = kt*32;
  u16* dst = Wt + (size_t)t*4096;
  #pragma unroll
  for (int s = 0; s < 2; ++s) {
    const int idx0 = (s*256 + (int)threadIdx.x)*8;
    const int ar = idx0 >> 5;
    const int w8 = (idx0 >> 3) & 3;
    const int sw = (ar >> 1) & 3;
    int kk = k0 + ((w8 ^ sw) << 3);
    const int n  = n0 + ar;
    const float* src = W;
    if (W2 && kk >= 256) { src = W2; kk -= 256; }
    union { u16 u[8]; s16x8 v; } o;
    #pragma unroll
    for (int e = 0; e < 8; ++e)
      o.u[e] = f2b(src[(size_t)(kk + e)*N + n]);
    *(s16x8*)(dst + idx0) = o.v;
  }
}

// ---------------------------------------------------------------------------
// bf16 MFMA GEMM, dual row-segment + dual col-segment bias. B staged via
// async global_load_lds from pre-tiled Wt. XCD-bijective block swizzle.
// ---------------------------------------------------------------------------
template<bool A1B, bool A2B, bool CB>
__global__ __launch_bounds__(256) void mmad_k(
    const void* __restrict__ A1a, const void* __restrict__ A1b,
    const void* __restrict__ A2a, const void* __restrict__ A2b, int K1,
    const u16* __restrict__ Wa, const u16* __restrict__ Wb,
    const float* __restrict__ bia, const float* __restrict__ bib,
    const float* __restrict__ bi2a, const float* __restrict__ bi2b, int Ns,
    const float* __restrict__ Ra, const float* __restrict__ Rb,
    void* __restrict__ Cp, int N, int K, int Mh, int doRelu)
{
  __shared__ u16 As[128*32];
  __shared__ u16 Bs[128*32];
  const int tid = threadIdx.x;
  const int lane = tid & 63, w = tid >> 6;
  const int gx = gridDim.x;
  const int nblk = gx * gridDim.y;
  int flat = blockIdx.y*gx + blockIdx.x;
  if (!(nblk & 7)) flat = (flat & 7)*(nblk >> 3) + (flat >> 3);
  const int bxx = flat % gx, byy = flat / gx;
  const int row0 = byy*128, col0 = bxx*128;
  const bool sec = (row0 >= Mh);
  const int lr0 = sec ? row0 - Mh : row0;
  const void* A1 = sec ? A1b : A1a;
  const void* A2 = sec ? A2b : A2a;
  const u16* Wt  = sec ? Wb : Wa;
  const float* bias  = sec ? bib : bia;
  const float* bias2 = sec ? bi2b : bi2a;
  const float* R = sec ? Rb : Ra;
  const int wr = (w >> 1)*64, wc = (w & 1)*64;
  const int ar = tid >> 1, ah = tid & 1;
  const int K2 = K - K1;
  const int ktn = K >> 5;
  f32x4 acc[4][4] = {};

  for (int kt = 0; kt < K; kt += 32) {
    {
      const u16* wtile = Wt + ((size_t)((col0 >> 7)*ktn + (kt >> 5)))*4096;
      #pragma unroll
      for (int s = 0; s < 2; ++s) {
        const u16* srcp = wtile + (size_t)(s*256 + tid)*8;
        __builtin_amdgcn_global_load_lds(
            (const __attribute__((address_space(1))) void*)srcp,
            (__attribute__((address_space(3))) void*)((char*)Bs + s*4096 + w*1024),
            16, 0, 0);
      }
    }
    const int kk = kt + ah*16;
    union { u16 u[16]; s16x8 v[2]; } tmp;
    if (kk < K1) {
      if constexpr (A1B) {
        const u16* ap = (const u16*)A1 + (size_t)(lr0+ar)*K1 + kk;
        tmp.v[0] = *(const s16x8*)ap; tmp.v[1] = *(const s16x8*)(ap+8);
      } else {
        const float* ap = (const float*)A1 + (size_t)(lr0+ar)*K1 + kk;
        #pragma unroll
        for (int i = 0; i < 16; i += 4) {
          f32x4 v4 = *(const f32x4*)(ap + i);
          tmp.u[i+0]=f2b(v4.x); tmp.u[i+1]=f2b(v4.y); tmp.u[i+2]=f2b(v4.z); tmp.u[i+3]=f2b(v4.w);
        }
      }
    } else {
      if constexpr (A2B) {
        const u16* ap = (const u16*)A2 + (size_t)(lr0+ar)*K2 + (kk - K1);
        tmp.v[0] = *(const s16x8*)ap; tmp.v[1] = *(const s16x8*)(ap+8);
      } else {
        const float* ap = (const float*)A2 + (size_t)(lr0+ar)*K2 + (kk - K1);
        #pragma unroll
        for (int i = 0; i < 16; i += 4) {
          f32x4 v4 = *(const f32x4*)(ap + i);
          tmp.u[i+0]=f2b(v4.x); tmp.u[i+1]=f2b(v4.y); tmp.u[i+2]=f2b(v4.z); tmp.u[i+3]=f2b(v4.w);
        }
      }
    }
    const int sw = (ar >> 1) & 3;
    *(s16x8*)(&As[ar*32 + ((ah*2+0)^sw)*8]) = tmp.v[0];
    *(s16x8*)(&As[ar*32 + ((ah*2+1)^sw)*8]) = tmp.v[1];
    __syncthreads();
    s16x8 af[4], bfv[4];
    #pragma unroll
    for (int fm = 0; fm < 4; ++fm) {
      const int r = wr + fm*16 + (lane & 15);
      const int g = (lane >> 4) ^ ((r >> 1) & 3);
      af[fm] = *(const s16x8*)(&As[r*32 + g*8]);
    }
    #pragma unroll
    for (int fn = 0; fn < 4; ++fn) {
      const int c = wc + fn*16 + (lane & 15);
      const int g = (lane >> 4) ^ ((c >> 1) & 3);
      bfv[fn] = *(const s16x8*)(&Bs[c*32 + g*8]);
    }
    #pragma unroll
    for (int fm = 0; fm < 4; ++fm)
      #pragma unroll
      for (int fn = 0; fn < 4; ++fn)
        acc[fm][fn] = __builtin_amdgcn_mfma_f32_16x16x32_bf16(af[fm], bfv[fn], acc[fm][fn], 0, 0, 0);
    __syncthreads();
  }

  #pragma unroll
  for (int fm = 0; fm < 4; ++fm) {
    const int ro = wr + fm*16 + (lane >> 4)*4;
    #pragma unroll
    for (int fn = 0; fn < 4; ++fn) {
      const int cc = col0 + wc + fn*16 + (lane & 15);
      const float bv = (cc < Ns) ? bias[cc] : bias2[cc - Ns];
      #pragma unroll
      for (int j = 0; j < 4; ++j) {
        float v = acc[fm][fn][j] + bv;
        if (R) v += R[(size_t)(lr0 + ro + j)*N + cc];
        if (doRelu) v = fmaxf(v, 0.f);
        const size_t idx = (size_t)(row0 + ro + j)*N + cc;
        if constexpr (CB) ((u16*)Cp)[idx] = f2b(v);
        else              ((float*)Cp)[idx] = v;
      }
    }
  }
}

// ---------------------------------------------------------------------------
// Preps (read bf16 qkv/kv): emit bf16 K [g][key][64], bf16 Vt [g][64][key],
// and Q (self: roped+0.125-prescaled bf16; s2s: raw f32; cross: K prescaled).
// ---------------------------------------------------------------------------
__global__ __launch_bounds__(256) void prep_self_k(
    const u16* __restrict__ qkvU, const float* __restrict__ t_enc,
    const float* __restrict__ s_enc,
    u16* __restrict__ Qb, u16* __restrict__ Kb, u16* __restrict__ Vt)
{
  __shared__ u16 vs[64][66];
  const int g = blockIdx.x >> 3, i0 = (blockIdx.x & 7)*64;
  const int h = g & 3, bn = g >> 2;
  const float* enc = (bn < 12) ? t_enc : s_enc;
  const int n = (bn < 12 ? bn : bn - 12) % kN;
  const int c = threadIdx.x & 63, t4 = threadIdx.x >> 6;
  const float sgn = (c & 1) ? 1.f : -1.f;
  #pragma unroll 4
  for (int rr = 0; rr < 16; ++rr) {
    const int il = rr*4 + t4, i = i0 + il;
    const u16* base = qkvU + ((size_t)bn*kM + i)*768 + h*192;
    const float q = b2f(base[c*3]), k = b2f(base[c*3+1]);
    const float qp = b2f(base[(c^1)*3]), kp = b2f(base[(c^1)*3+1]);
    const size_t eo = ((size_t)(n*kM + i))*kHD + c;
    const float e0 = enc[eo], e1 = enc[kEncSlab + eo];
    Qb[((size_t)g*kM + i)*kHD + c] = f2b((q*e0 + sgn*qp*e1)*0.125f);
    Kb[((size_t)g*kM + i)*kHD + c] = f2b(k*e0 + sgn*kp*e1);
    vs[il][c] = base[c*3+2];
  }
  __syncthreads();
  #pragma unroll 4
  for (int rr = 0; rr < 16; ++rr) {
    const int cc = rr*4 + t4;
    Vt[((size_t)g*kHD + cc)*kM + i0 + c] = vs[c][cc];
  }
}

__global__ __launch_bounds__(256) void prep_s2s_k(
    const u16* __restrict__ qkvU, const float* __restrict__ kenc,
    float* __restrict__ Qs, u16* __restrict__ Kb, u16* __restrict__ Vt)
{
  __shared__ u16 vs[64][66];
  const int g = blockIdx.x >> 3, i0 = (blockIdx.x & 7)*64;   // g = bh*6+view
  const int view = g % kN, bh = g / kN;
  const int h = bh & 3, b = bh >> 2;
  const int c = threadIdx.x & 63, t4 = threadIdx.x >> 6;
  const float sgn = (c & 1) ? 1.f : -1.f;
  #pragma unroll 4
  for (int rr = 0; rr < 16; ++rr) {
    const int il = rr*4 + t4, i = i0 + il;
    const u16* base = qkvU + ((size_t)(kRowsH + (b*kN+view)*kM + i))*768 + h*192;
    const float k = b2f(base[c*3+1]), kp = b2f(base[(c^1)*3+1]);
    const size_t eo = ((size_t)(view*kM + i))*kHD + c;
    const float e0 = kenc[eo], e1 = kenc[kEncSlab + eo];
    Qs[((size_t)g*kM + i)*kHD + c] = b2f(base[c*3]);
    Kb[((size_t)g*kM + i)*kHD + c] = f2b(k*e0 + sgn*kp*e1);
    vs[il][c] = base[c*3+2];
  }
  __syncthreads();
  #pragma unroll 4
  for (int rr = 0; rr < 16; ++rr) {
    const int cc = rr*4 + t4;
    Vt[((size_t)g*kHD + cc)*kM + i0 + c] = vs[c][cc];
  }
}

__global__ __launch_bounds__(256) void prep_cross_k(
    const u16* __restrict__ qkvC, u16* __restrict__ Kb, u16* __restrict__ Vt)
{
  __shared__ u16 vs[64][66];
  const int g = blockIdx.x >> 3, i0 = (blockIdx.x & 7)*64;
  const int h = g & 3, bn = g >> 2;
  const int src = (bn < 12) ? bn + 12 : bn - 12;
  const int c = threadIdx.x & 63, t4 = threadIdx.x >> 6;
  #pragma unroll 4
  for (int rr = 0; rr < 16; ++rr) {
    const int il = rr*4 + t4, i = i0 + il;
    const u16* base = qkvC + ((size_t)src*kM + i)*768 + 256 + h*128;
    Kb[((size_t)g*kM + i)*kHD + c] = f2b(b2f(base[c*2]) * 0.125f);
    vs[il][c] = base[c*2+1];
  }
  __syncthreads();
  #pragma unroll 4
  for (int rr = 0; rr < 16; ++rr) {
    const int cc = rr*4 + t4;
    Vt[((size_t)g*kHD + cc)*kM + i0 + c] = vs[c][cc];
  }
}

// ---------------------------------------------------------------------------
// self/cross attention: 32 q-rows/wave (2 fragments sharing K/V loads),
// online softmax + defer-max; P redistribution via E/F/G/H (byte-verified).
// 384 blocks, XCD-bijective.
// ---------------------------------------------------------------------------
template<int CROSSQ>
__global__ __launch_bounds__(256) void attn_mm_k(
    const u16* __restrict__ Qb, const u16* __restrict__ Kb,
    const u16* __restrict__ Vt, u16* __restrict__ ctx)
{
  const int w = threadIdx.x >> 6, lane = threadIdx.x & 63;
  const int bij = (blockIdx.x & 7)*48 + (blockIdx.x >> 3);   // 384
  const int g = bij >> 2, qblk = bij & 3;
  const int h = g & 3, bn = g >> 2;
  const int q0 = qblk*128 + w*32;
  const int qr = lane & 15, hi = lane >> 4;
  const bool subhi = (hi & 1), up = (hi >= 2);

  s16x8 qf0[2], qf1[2];
  #pragma unroll
  for (int f = 0; f < 2; ++f) {
    const u16* qp = CROSSQ
      ? Qb + ((size_t)(bn*kM + q0 + f*16 + qr))*768 + h*kHD + hi*8
      : Qb + ((size_t)g*kM + q0 + f*16 + qr)*kHD + hi*8;
    qf0[f] = *(const s16x8*)(qp);
    qf1[f] = *(const s16x8*)(qp + 32);
  }

  const u16* Kg = Kb + (size_t)g*kM*kHD;
  const u16* Vg = Vt + (size_t)g*kHD*kM;
  f32x4 acc[2][4] = {};
  float m[2] = {-1e30f, -1e30f}, l[2] = {0.f, 0.f};

  for (int kc = 0; kc < 16; ++kc) {
    const int k0 = kc*32;
    s16x8 a0[2], a1[2];
    #pragma unroll
    for (int t = 0; t < 2; ++t) {
      const u16* kp = Kg + ((size_t)(k0 + t*16 + qr))*kHD + hi*8;
      a0[t] = *(const s16x8*)(kp);
      a1[t] = *(const s16x8*)(kp + 32);
    }
    s16x8 pa[2];
    #pragma unroll
    for (int f = 0; f < 2; ++f) {
      f32x4 st[2];
      #pragma unroll
      for (int t = 0; t < 2; ++t) {
        f32x4 z = {0.f, 0.f, 0.f, 0.f};
        z = __builtin_amdgcn_mfma_f32_16x16x32_bf16(a0[t], qf0[f], z, 0, 0, 0);
        z = __builtin_amdgcn_mfma_f32_16x16x32_bf16(a1[t], qf1[f], z, 0, 0, 0);
        st[t] = z;
      }
      float mloc = fmaxf(fmaxf(fmaxf(st[0][0], st[0][1]), fmaxf(st[0][2], st[0][3])),
                         fmaxf(fmaxf(st[1][0], st[1][1]), fmaxf(st[1][2], st[1][3])));
      mloc = fmaxf(mloc, __shfl_xor(mloc, 16));
      mloc = fmaxf(mloc, __shfl_xor(mloc, 32));
      if (!__all(mloc - m[f] <= 8.f)) {
        const float mn = fmaxf(m[f], mloc);
        const float r = exp2f((m[f] - mn)*kL2E);
        m[f] = mn;
        l[f] *= r;
        const float rr0 = __shfl(r, hi*4+0), rr1 = __shfl(r, hi*4+1);
        const float rr2 = __shfl(r, hi*4+2), rr3 = __shfl(r, hi*4+3);
        #pragma unroll
        for (int db = 0; db < 4; ++db) {
          acc[f][db][0] *= rr0; acc[f][db][1] *= rr1;
          acc[f][db][2] *= rr2; acc[f][db][3] *= rr3;
        }
      }
      float p[8], ls = 0.f;
      #pragma unroll
      for (int t = 0; t < 2; ++t)
        #pragma unroll
        for (int j = 0; j < 4; ++j) {
          const float pv = exp2f((st[t][j] - m[f])*kL2E);
          p[t*4+j] = pv; ls += pv;
        }
      l[f] += ls;
      const unsigned c00 = pk2(p[0], p[1]);
      const unsigned c01 = pk2(p[2], p[3]);
      const unsigned c10 = pk2(p[4], p[5]);
      const unsigned c11 = pk2(p[6], p[7]);
      const unsigned c00x = __shfl_xor((int)c00, 32), c10x = __shfl_xor((int)c10, 32);
      const unsigned c01x = __shfl_xor((int)c01, 32), c11x = __shfl_xor((int)c11, 32);
      const unsigned E = up ? c10x : c00, F = up ? c10 : c00x;
      const unsigned G = up ? c11x : c01, H = up ? c11 : c01x;
      const unsigned Ex = __shfl_xor((int)E, 16), Fx = __shfl_xor((int)F, 16);
      const unsigned Gx = __shfl_xor((int)G, 16), Hx = __shfl_xor((int)H, 16);
      union { unsigned w[4]; s16x8 v; } pw;
      pw.w[0] = subhi ? Fx : E;
      pw.w[1] = subhi ? Hx : G;
      pw.w[2] = subhi ? F  : Ex;
      pw.w[3] = subhi ? H  : Gx;
      pa[f] = pw.v;
    }
    #pragma unroll
    for (int db = 0; db < 4; ++db) {
      const u16* vp = Vg + ((size_t)(db*16 + qr))*kM + k0 + hi*8;
      const s16x8 vf = *(const s16x8*)(vp);
      acc[0][db] = __builtin_amdgcn_mfma_f32_16x16x32_bf16(pa[0], vf, acc[0][db], 0, 0, 0);
      acc[1][db] = __builtin_amdgcn_mfma_f32_16x16x32_bf16(pa[1], vf, acc[1][db], 0, 0, 0);
    }
  }

  #pragma unroll
  for (int f = 0; f < 2; ++f) {
    float lf = l[f];
    lf += __shfl_xor(lf, 16); lf += __shfl_xor(lf, 32);
    const float li = 1.f/lf;
    const float l0 = __shfl(li, hi*4+0), l1 = __shfl(li, hi*4+1);
    const float l2 = __shfl(li, hi*4+2), l3 = __shfl(li, hi*4+3);
    #pragma unroll
    for (int db = 0; db < 4; ++db) {
      const size_t base = ((size_t)(bn*kM + q0 + f*16 + hi*4))*kD + h*kHD + db*16 + qr;
      ctx[base + 0*kD] = f2b(acc[f][db][0]*l0);
      ctx[base + 1*kD] = f2b(acc[f][db][1]*l1);
      ctx[base + 2*kD] = f2b(acc[f][db][2]*l2);
      ctx[base + 3*kD] = f2b(acc[f][db][3]*l3);
    }
  }
}

__device__ __forceinline__ void rope4(const f32x4 x, const f32x4 e0, const f32x4 e1, float o[4])
{
  o[0] = x[0]*e0[0] - x[1]*e1[0];
  o[1] = x[1]*e0[1] + x[0]*e1[1];
  o[2] = x[2]*e0[2] - x[3]*e1[2];
  o[3] = x[3]*e0[3] + x[2]*e1[3];
}

// ---------------------------------------------------------------------------
// s2s: 32 q-rows per wave (2 fragments sharing all K/V loads), online
// softmax + defer-max. block = (bh, col, qblk(128 rows), split); 960 blocks.
// ---------------------------------------------------------------------------
__global__ __launch_bounds__(256) void attn_s2s_k(
    const float* __restrict__ Qraw, const u16* __restrict__ Kb,
    const u16* __restrict__ Vt, const float* __restrict__ qenc,
    u16* __restrict__ ctx5)
{
  const int w = threadIdx.x >> 6, lane = threadIdx.x & 63;
  const int bij = (blockIdx.x & 7)*120 + (blockIdx.x >> 3);  // 960
  const int bh = bij / 120;
  const int rest = bij % 120;
  const int col = rest / 20;
  const int rem = rest % 20;
  const int qblk = rem / 5, split = rem % 5;
  const int q0 = qblk*128 + w*32;
  const int qr = lane & 15, hi = lane >> 4;
  const bool subhi = (hi & 1), up = (hi >= 2);

  const int e  = split*6 + col;
  const int iv = e/5;
  const int j0 = e%5;
  const int jv = j0 + (j0 >= iv ? 1 : 0);

  s16x8 qf0[2], qf1[2];
  #pragma unroll
  for (int f = 0; f < 2; ++f) {
    const float* qp = Qraw + ((size_t)(bh*kN + jv)*kM + q0 + f*16 + qr)*kHD + hi*8;
    const float* ep = qenc + ((size_t)(iv*kN + jv))*kHD + hi*8;
    union { u16 u[8]; s16x8 v; } A, B;
    float o[4];
    rope4(*(const f32x4*)(qp),   *(const f32x4*)(ep),   *(const f32x4*)(ep+kQEncSlab), o);
    #pragma unroll
    for (int j = 0; j < 4; ++j) A.u[j] = f2b(o[j]*0.125f);
    rope4(*(const f32x4*)(qp+4), *(const f32x4*)(ep+4), *(const f32x4*)(ep+kQEncSlab+4), o);
    #pragma unroll
    for (int j = 0; j < 4; ++j) A.u[4+j] = f2b(o[j]*0.125f);
    rope4(*(const f32x4*)(qp+32), *(const f32x4*)(ep+32), *(const f32x4*)(ep+kQEncSlab+32), o);
    #pragma unroll
    for (int j = 0; j < 4; ++j) B.u[j] = f2b(o[j]*0.125f);
    rope4(*(const f32x4*)(qp+36), *(const f32x4*)(ep+36), *(const f32x4*)(ep+kQEncSlab+36), o);
    #pragma unroll
    for (int j = 0; j < 4; ++j) B.u[4+j] = f2b(o[j]*0.125f);
    qf0[f] = A.v; qf1[f] = B.v;
  }

  const int g2 = bh*kN + iv;
  const u16* Kg = Kb + (size_t)g2*kM*kHD;
  const u16* Vg = Vt + (size_t)g2*kHD*kM;
  f32x4 acc[2][4] = {};
  float m[2] = {-1e30f, -1e30f}, l[2] = {0.f, 0.f};

  for (int kc = 0; kc < 16; ++kc) {
    const int k0 = kc*32;
    s16x8 a0[2], a1[2];
    #pragma unroll
    for (int t = 0; t < 2; ++t) {
      const u16* kp = Kg + ((size_t)(k0 + t*16 + qr))*kHD + hi*8;
      a0[t] = *(const s16x8*)(kp);
      a1[t] = *(const s16x8*)(kp + 32);
    }
    s16x8 pa[2];
    #pragma unroll
    for (int f = 0; f < 2; ++f) {
      f32x4 st[2];
      #pragma unroll
      for (int t = 0; t < 2; ++t) {
        f32x4 z = {0.f, 0.f, 0.f, 0.f};
        z = __builtin_amdgcn_mfma_f32_16x16x32_bf16(a0[t], qf0[f], z, 0, 0, 0);
        z = __builtin_amdgcn_mfma_f32_16x16x32_bf16(a1[t], qf1[f], z, 0, 0, 0);
        st[t] = z;
      }
      float mloc = fmaxf(fmaxf(fmaxf(st[0][0], st[0][1]), fmaxf(st[0][2], st[0][3])),
                         fmaxf(fmaxf(st[1][0], st[1][1]), fmaxf(st[1][2], st[1][3])));
      mloc = fmaxf(mloc, __shfl_xor(mloc, 16));
      mloc = fmaxf(mloc, __shfl_xor(mloc, 32));
      if (!__all(mloc - m[f] <= 8.f)) {
        const float mn = fmaxf(m[f], mloc);
        const float r = exp2f((m[f] - mn)*kL2E);
        m[f] = mn;
        l[f] *= r;
        const float rr0 = __shfl(r, hi*4+0), rr1 = __shfl(r, hi*4+1);
        const float rr2 = __shfl(r, hi*4+2), rr3 = __shfl(r, hi*4+3);
        #pragma unroll
        for (int db = 0; db < 4; ++db) {
          acc[f][db][0] *= rr0; acc[f][db][1] *= rr1;
          acc[f][db][2] *= rr2; acc[f][db][3] *= rr3;
        }
      }
      float p[8], ls = 0.f;
      #pragma unroll
      for (int t = 0; t < 2; ++t)
        #pragma unroll
        for (int j = 0; j < 4; ++j) {
          const float pv = exp2f((st[t][j] - m[f])*kL2E);
          p[t*4+j] = pv; ls += pv;
        }
      l[f] += ls;
      const unsigned c00 = pk2(p[0], p[1]);
      const unsigned c01 = pk2(p[2], p[3]);
      const unsigned c10 = pk2(p[4], p[5]);
      const unsigned c11 = pk2(p[6], p[7]);
      const unsigned c00x = __shfl_xor((int)c00, 32), c10x = __shfl_xor((int)c10, 32);
      const unsigned c01x = __shfl_xor((int)c01, 32), c11x = __shfl_xor((int)c11, 32);
      const unsigned E = up ? c10x : c00, F = up ? c10 : c00x;
      const unsigned G = up ? c11x : c01, H = up ? c11 : c01x;
      const unsigned Ex = __shfl_xor((int)E, 16), Fx = __shfl_xor((int)F, 16);
      const unsigned Gx = __shfl_xor((int)G, 16), Hx = __shfl_xor((int)H, 16);
      union { unsigned w[4]; s16x8 v; } pw;
      pw.w[0] = subhi ? Fx : E;
      pw.w[1] = subhi ? Hx : G;
      pw.w[2] = subhi ? F  : Ex;
      pw.w[3] = subhi ? H  : Gx;
      pa[f] = pw.v;
    }
    #pragma unroll
    for (int db = 0; db < 4; ++db) {
      const u16* vp = Vg + ((size_t)(db*16 + qr))*kM + k0 + hi*8;
      const s16x8 vf = *(const s16x8*)(vp);
      acc[0][db] = __builtin_amdgcn_mfma_f32_16x16x32_bf16(pa[0], vf, acc[0][db], 0, 0, 0);
      acc[1][db] = __builtin_amdgcn_mfma_f32_16x16x32_bf16(pa[1], vf, acc[1][db], 0, 0, 0);
    }
  }

  const int b = bh >> 2, h = bh & 3;
  u16* outp = ctx5 + (size_t)split*kTOK;
  #pragma unroll
  for (int f = 0; f < 2; ++f) {
    float lf = l[f];
    lf += __shfl_xor(lf, 16); lf += __shfl_xor(lf, 32);
    const float li = 0.2f/lf;
    const float l0 = __shfl(li, hi*4+0), l1 = __shfl(li, hi*4+1);
    const float l2 = __shfl(li, hi*4+2), l3 = __shfl(li, hi*4+3);
    #pragma unroll
    for (int db = 0; db < 4; ++db) {
      const size_t base = ((size_t)((b*kN + col)*kM + q0 + f*16 + hi*4))*kD + h*kHD + db*16 + qr;
      outp[base + 0*kD] = f2b(acc[f][db][0]*l0);
      outp[base + 1*kD] = f2b(acc[f][db][1]*l1);
      outp[base + 2*kD] = f2b(acc[f][db][2]*l2);
      outp[base + 3*kD] = f2b(acc[f][db][3]*l3);
    }
  }
}

__global__ __launch_bounds__(256) void sum5_k(const u16* __restrict__ c5,
                                              u16* __restrict__ outU)
{
  const size_t i4 = ((size_t)blockIdx.x*256 + threadIdx.x)*4;
  float s0=0.f, s1=0.f, s2=0.f, s3=0.f;
  #pragma unroll
  for (int sp = 0; sp < 5; ++sp) {
    uint2 d = *(const uint2*)(c5 + sp*kTOK + i4);
    s0 += b2f((u16)(d.x & 0xffff)); s1 += b2f((u16)(d.x >> 16));
    s2 += b2f((u16)(d.y & 0xffff)); s3 += b2f((u16)(d.y >> 16));
  }
  union { u16 u[4]; uint2 d; } o;
  o.u[0]=f2b(s0); o.u[1]=f2b(s1); o.u[2]=f2b(s2); o.u[3]=f2b(s3);
  *(uint2*)(outU + i4) = o.d;
}

// t2t attention: wave per (b,h,nq,m) — 24576 waves.
__global__ __launch_bounds__(256) void attn_t2t_k(
    const u16* __restrict__ qkvU, u16* __restrict__ ctxU)
{
  const int wid = blockIdx.x*4 + (threadIdx.x >> 6);
  const int lane = threadIdx.x & 63;
  const int m = wid & 511;
  const int t = wid >> 9;
  const int nq = t % kN;
  const int bh = t / kN;
  const int h = bh & 3, b = bh >> 2;
  const u16* pb[kN];
  #pragma unroll
  for (int nk = 0; nk < kN; ++nk)
    pb[nk] = qkvU + ((size_t)(b*kN+nk)*kM + m)*768 + h*192;
  const float qc = b2f(pb[nq][lane*3]);
  float sim[kN];
  #pragma unroll
  for (int nk = 0; nk < kN; ++nk)
    sim[nk] = wred_sum(qc * b2f(pb[nk][lane*3+1])) * 0.125f;
  float mx = sim[0];
  #pragma unroll
  for (int nk = 1; nk < kN; ++nk) mx = fmaxf(mx, sim[nk]);
  float p[kN], s = 0.f;
  #pragma unroll
  for (int nk = 0; nk < kN; ++nk) { p[nk] = expf(sim[nk]-mx); s += p[nk]; }
  const float inv = 1.f/s;
  float o = 0.f;
  #pragma unroll
  for (int nk = 0; nk < kN; ++nk) o = fmaf(p[nk], b2f(pb[nk][lane*3+2]), o);
  ctxU[((size_t)(b*kN+nq)*kM + m)*kD + h*kHD + lane] = f2b(o*inv);
}

// LayerNorm(512) + exact GELU: reads f32, writes bf16 (separate buffer).
__global__ __launch_bounds__(256) void lngelu_k(
    const float* __restrict__ x, u16* __restrict__ y,
    const float* __restrict__ g0, const float* __restrict__ b0,
    const float* __restrict__ g1, const float* __restrict__ b1, int Mh)
{
  const int row = blockIdx.x;
  const int tid = threadIdx.x;
  const float* g = (row < Mh) ? g0 : g1;
  const float* bb = (row < Mh) ? b0 : b1;
  const float* xr = x + (size_t)row*512;
  const float v0 = xr[tid], v1 = xr[tid+256];
  const int w = tid >> 6, lane = tid & 63;
  __shared__ float red[2][4];
  const float s1 = wred_sum(v0+v1);
  const float s2 = wred_sum(v0*v0+v1*v1);
  if (lane == 0){ red[0][w]=s1; red[1][w]=s2; }
  __syncthreads();
  const float mean = (red[0][0]+red[0][1]+red[0][2]+red[0][3]) * (1.f/512.f);
  const float ms   = (red[1][0]+red[1][1]+red[1][2]+red[1][3]) * (1.f/512.f);
  const float rs = rsqrtf(ms - mean*mean + 1e-5f);
  const float y0 = (v0-mean)*rs*g[tid]     + bb[tid];
  const float y1 = (v1-mean)*rs*g[tid+256] + bb[tid+256];
  y[(size_t)row*512 + tid]     = f2b(0.5f*y0*(1.f+erff(y0*0.70710678118654752f)));
  y[(size_t)row*512 + tid+256] = f2b(0.5f*y1*(1.f+erff(y1*0.70710678118654752f)));
}

__global__ void conf_dot_k(const float* __restrict__ tmp, const float* __restrict__ w2,
                           const float* __restrict__ b2, float* __restrict__ out)
{
  const int w = threadIdx.x >> 6, lane = threadIdx.x & 63;
  const int row = blockIdx.x*4 + w;
  const float* t = tmp + (size_t)row*kD;
  float s = 0.f;
  #pragma unroll
  for (int j=0;j<4;++j) s = fmaf(t[lane+j*64], w2[lane+j*64], s);
  s = wred_sum(s);
  if (lane == 0) out[row] = s + b2[0];
}

// ---------------------------------------------------------------------------
extern "C" void kernel_launch(void* const* d_in, const int* in_sizes, int n_in,
                              void* d_out, int out_size, void* d_ws, size_t ws_size,
                              hipStream_t stream)
{
  auto F = [&](int i){ return (const float*)d_in[i]; };
  const float* t_desc = F(0);
  const float* s_desc = F(1);
  const float* t_enc  = F(2);
  const float* s_enc  = F(3);
  const float* q_enc  = F(4);
  const float* k_enc  = F(5);

  // ---- workspace map ----
  char* base = (char*)d_ws;
  float* xts = (float*)base;                     // 12288x256 f32 (xt|xs)
  float* xt = xts;
  float* xs = xts + kTOK;
  char* R1  = base + 2*kTOK*sizeof(float);       // 25.17 MB multi-use
  char* CTX = R1 + 4*kTOK*sizeof(float);         // 6.29 MB
  char* MSG = CTX + 2*kTOK*sizeof(u16);          // 6.29 MB
  u16* Qb16 = (u16*)(MSG + kTOK*sizeof(float));
  u16* Kb16 = Qb16 + 2*kTOK;
  u16* Vt16 = Kb16 + 2*kTOK;
  u16* wsW  = Vt16 + 2*kTOK;
  // aliases
  u16*   qkvU  = (u16*)R1;                       // 12288x768
  float* hbuf  = (float*)R1;                     // 12288x512 f32
  u16*   ctx5  = (u16*)R1;                       // 5 x 6144x256 bf16 (s2s partials)
  float* Wtmp  = (float*)R1;                     // 4 x 256x512 f32 (prep-time only)
  u16*   ctxU  = (u16*)CTX;                      // 12288x256
  float* Qs2s  = (float*)MSG;                    // 48x512x64 f32
  float* confb = (float*)MSG;                    // 6144x256 f32
  u16*   yU    = (u16*)CTX;                      // 12288x512 (spans CTX+MSG)

  float* out_t2s2 = (float*)d_out;
  float* out_conf = (float*)d_out + 2*kTOK;

  // ---- fused-FFN weight precompute (W' = Wout @ W1_bot, b1') ----
  // sets: 0=SA, 1=SS, 2=TT, 3=CA
  // ---- weight cast table (tiled Bs-image layout) ----
  WtTable tab;
  int nd = 0, total_tiles = 0;
  size_t woff = 0;
  const u16* wp[18];
  auto addw = [&](int idx, const float* W2, int K, int N){
    u16* dst = wsW + woff;
    tab.d[nd] = { F(idx), W2, dst, K, N, (N>>7)*(K>>5) };
    total_tiles += tab.d[nd].ntiles;
    wp[nd] = dst;
    woff += (size_t)K*N;
    ++nd;
    return nd-1;
  };
  const int W_SA_QKV = addw(6,  nullptr, 256, 768);
  const int W_SA_F1  = addw(10, Wtmp + 0*131072, 512, 512);
  const int W_SA_F2  = addw(14, nullptr, 512, 256);
  const int W_SS_QKV = addw(16, nullptr, 256, 768);
  const int W_SS_F1  = addw(20, Wtmp + 1*131072, 512, 512);
  const int W_SS_F2  = addw(24, nullptr, 512, 256);
  const int W_TT_QKV = addw(26, nullptr, 256, 768);
  const int W_TT_F1  = addw(30, Wtmp + 2*131072, 512, 512);
  const int W_TT_F2  = addw(34, nullptr, 512, 256);
  const int W_CA_Q   = addw(36, nullptr, 256, 256);  // contiguous with W_CA_KV
  const int W_CA_KV  = addw(38, nullptr, 256, 512);
  const int W_CA_F1  = addw(42, Wtmp + 3*131072, 512, 512);
  const int W_CA_F2  = addw(46, nullptr, 512, 256);
  const int W_CF_1   = addw(48, nullptr, 256, 256);
  (void)W_CA_KV;
  float* b1p = (float*)(wsW + woff);             // 4 x 512 f32 fused biases

  FuseArgs fa;
  fa.Wout[0]=F(8);  fa.Wout[1]=F(18); fa.Wout[2]=F(28); fa.Wout[3]=F(40);
  fa.W1[0]=F(10);   fa.W1[1]=F(20);   fa.W1[2]=F(30);   fa.W1[3]=F(42);
  fa.bout[0]=F(9);  fa.bout[1]=F(19); fa.bout[2]=F(29); fa.bout[3]=F(41);
  fa.b1[0]=F(11);   fa.b1[1]=F(21);   fa.b1[2]=F(31);   fa.b1[3]=F(43);
  fa.Wtmp = Wtmp; fa.b1p = b1p;
  wfuse_k<<<128, 256, 0, stream>>>(fa);
  biasfuse_k<<<8, 256, 0, stream>>>(fa);
  wtcast_k<<<total_tiles, 256, 0, stream>>>(tab);

  // mmad launchers (dual row-segment, 12288 rows)
  auto mm_f32_to_b16 = [&](const float* a1a, const float* a1b, int wa, int wb2,
                           const float* ba, const float* bb2, u16* c, int N_, int K_){
    dim3 grid(N_/128, kRows/128);
    mmad_k<false,false,true><<<grid,256,0,stream>>>(a1a, a1b, nullptr, nullptr, K_,
        wp[wa], wp[wb2], ba, bb2, ba, bb2, N_, nullptr, nullptr, c, N_, K_, kRowsH, 0);
  };
  // fused f1: A = concat(x f32, ctx bf16), W = [W1_top; W'], bias = b1'
  auto mm_f1 = [&](const float* a1a, const float* a1b, const u16* a2a, const u16* a2b,
                   int wa, int wb2, const float* ba, const float* bb2, float* c){
    dim3 grid(512/128, kRows/128);
    mmad_k<false,true,false><<<grid,256,0,stream>>>(a1a, a1b, a2a, a2b, 256,
        wp[wa], wp[wb2], ba, bb2, ba, bb2, 512, nullptr, nullptr, c, 512, 512, kRowsH, 0);
  };
  auto mm_f2 = [&](const u16* a1a, const u16* a1b, int wa, int wb2,
                   const float* ba, const float* bb2,
                   const float* ra, const float* rb, float* c){
    dim3 grid(256/128, kRows/128);
    mmad_k<true,false,false><<<grid,256,0,stream>>>(a1a, a1b, nullptr, nullptr, 512,
        wp[wa], wp[wb2], ba, bb2, ba, bb2, 256, ra, rb, c, 256, 512, kRowsH, 0);
  };

  // ================= SELF (t || s, shared sa weights) =================
  mm_f32_to_b16(t_desc, s_desc, W_SA_QKV, W_SA_QKV, F(7), F(7), qkvU, 768, 256);
  prep_self_k<<<kGrp*8, 256, 0, stream>>>(qkvU, t_enc, s_enc, Qb16, Kb16, Vt16);
  attn_mm_k<0><<<384, 256, 0, stream>>>(Qb16, Kb16, Vt16, ctxU);
  mm_f1(t_desc, s_desc, ctxU, ctxU + kTOK, W_SA_F1, W_SA_F1, b1p+0*512, b1p+0*512, hbuf);
  lngelu_k<<<kRows, 256, 0, stream>>>(hbuf, yU, F(12), F(13), F(12), F(13), kRowsH);
  mm_f2(yU, yU + (size_t)kRowsH*512, W_SA_F2, W_SA_F2, F(15), F(15), t_desc, s_desc, xts);

  // ================= TT (t) || SS (s) =================
  mm_f32_to_b16(xt, xs, W_TT_QKV, W_SS_QKV, F(27), F(17), qkvU, 768, 256);
  prep_s2s_k<<<kGrpH*8, 256, 0, stream>>>(qkvU, k_enc, Qs2s, Kb16, Vt16);
  attn_t2t_k<<<(kB*kH*kN*kM)/4, 256, 0, stream>>>(qkvU, ctxU);
  attn_s2s_k<<<960, 256, 0, stream>>>(Qs2s, Kb16, Vt16, q_enc, ctx5);
  sum5_k<<<(int)(kTOK/1024), 256, 0, stream>>>(ctx5, ctxU + kTOK);
  mm_f1(xt, xs, ctxU, ctxU + kTOK, W_TT_F1, W_SS_F1, b1p+2*512, b1p+1*512, hbuf);
  lngelu_k<<<kRows, 256, 0, stream>>>(hbuf, yU, F(32), F(33), F(22), F(23), kRowsH);
  mm_f2(yU, yU + (size_t)kRowsH*512, W_TT_F2, W_SS_F2, F(35), F(25), xt, xs, xts);

  // ================= CONF (from xs post-s2s) =================
  {
    dim3 grid(2, kRowsH/128);
    mmad_k<false,false,false><<<grid,256,0,stream>>>(xs, xs, nullptr, nullptr, 256,
        wp[W_CF_1], wp[W_CF_1], F(49), F(49), F(49), F(49), 256,
        nullptr, nullptr, confb, 256, 256, kRowsH, 1);
  }
  conf_dot_k<<<kRowsH/4, 256, 0, stream>>>(confb, F(50), F(51), out_conf);

  // ================= CROSS (merged q+kv GEMM) =================
  {
    dim3 grid(768/128, kRows/128);
    mmad_k<false,false,true><<<grid,256,0,stream>>>(xt, xs, nullptr, nullptr, 256,
        wp[W_CA_Q], wp[W_CA_Q], F(37), F(37), F(39), F(39), 256,
        nullptr, nullptr, qkvU, 768, 256, kRowsH, 0);
  }
  prep_cross_k<<<kGrp*8, 256, 0, stream>>>(qkvU, Kb16, Vt16);
  attn_mm_k<1><<<384, 256, 0, stream>>>(qkvU, Kb16, Vt16, ctxU);
  mm_f1(xt, xs, ctxU, ctxU + kTOK, W_CA_F1, W_CA_F1, b1p+3*512, b1p+3*512, hbuf);
  lngelu_k<<<kRows, 256, 0, stream>>>(hbuf, yU, F(44), F(45), F(44), F(45), kRowsH);
  mm_f2(yU, yU + (size_t)kRowsH*512, W_CA_F2, W_CA_F2, F(47), F(47), xt, xs, out_t2s2);
}